// Round 7
// baseline (134.796 us; speedup 1.0000x reference)
//
#include <hip/hip_runtime.h>
#include <math.h>

#define NN  8
#define CIN 128
#define HW  1296
#define CC  256
#define DDS 1156

typedef __attribute__((ext_vector_type(8))) short bvec8;
typedef __attribute__((ext_vector_type(4))) float fvec4;

__device__ __forceinline__ float sigmoidf_(float x) {
    return 1.f / (1.f + __expf(-x));
}
__device__ __forceinline__ float tanhf_(float x) {
    float xa = fminf(fmaxf(x, -15.f), 15.f);
    float e = __expf(2.f * xa);
    return (e - 1.f) / (e + 1.f);
}
__device__ __forceinline__ unsigned short f2bf(float f) {
    unsigned int u = __float_as_uint(f);
    u = (u + 0x7FFFu + ((u >> 16) & 1u)) >> 16;
    return (unsigned short)u;
}
__device__ __forceinline__ unsigned int cvtpk_bf16(float a, float b) {
    unsigned int r;
    asm("v_cvt_pk_bf16_f32 %0, %1, %2" : "=v"(r) : "v"(a), "v"(b));
    return r;   // lo16 = bf16(a), hi16 = bf16(b), RTNE
}
__device__ __forceinline__ float exp2a(float x) {   // 2^x, single v_exp_f32
    float r;
    asm("v_exp_f32 %0, %1" : "=v"(r) : "v"(x));
    return r;
}

// ---------------- kernel 0: prep ----------------
__global__ __launch_bounds__(256) void k_prep(
        const float* __restrict__ x, const float* __restrict__ h0,
        const float* __restrict__ Wx,
        const float* __restrict__ Wq, const float* __restrict__ Wk,
        const float* __restrict__ Wv, const float* __restrict__ tau,
        const float* __restrict__ Wi2, const float* __restrict__ Wf2,
        const float* __restrict__ Wg2, const float* __restrict__ Wo2,
        const float* __restrict__ Wi1, const float* __restrict__ Wf1,
        const float* __restrict__ Wg1, const float* __restrict__ Wo1,
        unsigned short* __restrict__ xb, unsigned short* __restrict__ h0b,
        unsigned short* __restrict__ apx, unsigned short* __restrict__ apq,
        unsigned short* __restrict__ apg2, unsigned short* __restrict__ apg1) {
    __shared__ float tr[10400];          // 8 ch x stride 1300 (bank-clean)
    int bid = blockIdx.x;
    int tid = threadIdx.x;
    if (bid < 384) {
        int n = bid / 48, cb = bid % 48;
        const float* src = (cb < 16) ? x  + (size_t)(n * CIN + cb * 8) * HW
                                     : h0 + (size_t)(n * CC + (cb - 16) * 8) * HW;
        unsigned short* dst = (cb < 16) ? xb  + ((size_t)(n * 16 + cb) * HW) * 8
                                        : h0b + ((size_t)(n * 32 + (cb - 16)) * HW) * 8;
        #pragma unroll
        for (int c = 0; c < 8; ++c)
            for (int p4 = tid; p4 < 324; p4 += 256) {
                float4 v = ((const float4*)(src + (size_t)c * HW))[p4];
                *(float4*)&tr[c * 1300 + p4 * 4] = v;
            }
        __syncthreads();
        for (int p = tid; p < 1296; p += 256) {
            union { unsigned short us[8]; bvec8 v; } pk;
            #pragma unroll
            for (int c = 0; c < 8; ++c) pk.us[c] = f2bf(tr[c * 1300 + p]);
            *(bvec8*)(dst + (size_t)p * 8) = pk.v;
        }
        return;
    }
    int t = (bid - 384) * 256 + tid;
    union { unsigned short us[8]; bvec8 v; } pk;
    if (t < 55296) {                        // apq (Wq scaled by tau*log2e)
        int u = t;
        int lane = u & 63;
        int t2 = u >> 6;
        int mf = t2 % 6, t3 = t2 / 6;
        int s = t3 % 18, g = t3 / 18;
        int kyx = s >> 1, icb = s & 1;
        int ky = kyx / 3, kx = kyx % 3;
        int m = mf * 16 + (lane & 15);
        int conv = m >> 5, cl = m & 31, co = g * 32 + cl;
        int ic0 = icb * 32 + (lane >> 4) * 8;
        const float* W = (conv == 0) ? Wq : (conv == 1 ? Wk : Wv);
        float scale = (conv == 0) ? tau[g] * 1.4426950408889634f : 1.f;
        #pragma unroll
        for (int j = 0; j < 8; ++j)
            pk.us[j] = f2bf(W[((co * 64 + ic0 + j) * 3 + ky) * 3 + kx] * scale);
        *(bvec8*)(apq + (size_t)u * 8) = pk.v;
    } else if (t < 59392) {                 // apx
        int u = t - 55296;
        int lane = u & 63;
        int t2 = u >> 6;
        int mf = t2 % 16, s = t2 / 16;
        int co = mf * 16 + (lane & 15);
        int k0 = s * 32 + (lane >> 4) * 8;
        #pragma unroll
        for (int j = 0; j < 8; ++j)
            pk.us[j] = f2bf(Wx[co * CIN + k0 + j]);
        *(bvec8*)(apx + (size_t)u * 8) = pk.v;
    } else if (t < 133120) {                // apg2
        int u = t - 59392;
        int lane = u & 63;
        int t2 = u >> 6;
        int mf = t2 % 8, t3 = t2 / 8;
        int s = t3 % 18, g = t3 / 18;
        int kyx = s >> 1, icb = s & 1;
        int ky = kyx / 3, kx = kyx % 3;
        int m = mf * 16 + (lane & 15);
        int gate = m >> 5, cl = m & 31, co = g * 32 + cl;
        int ic0 = icb * 32 + (lane >> 4) * 8;
        const float* W = (gate == 0) ? Wi2 : (gate == 1 ? Wf2 : (gate == 2 ? Wg2 : Wo2));
        #pragma unroll
        for (int j = 0; j < 8; ++j)
            pk.us[j] = f2bf(W[((co * 64 + ic0 + j) * 3 + ky) * 3 + kx]);
        *(bvec8*)(apg2 + (size_t)u * 8) = pk.v;
    } else if (t < 137216) {                // apg1
        int u = t - 133120;
        int lane = u & 63;
        int t2 = u >> 6;
        int mf = t2 % 8, g = t2 / 8;
        int m = mf * 16 + (lane & 15);
        int gate = m >> 5, cl = m & 31, co = g * 32 + cl;
        int k0 = (lane >> 4) * 8;
        const float* W = (gate == 0) ? Wi1 : (gate == 1 ? Wf1 : (gate == 2 ? Wg1 : Wo1));
        #pragma unroll
        for (int j = 0; j < 8; ++j)
            pk.us[j] = f2bf(W[co * 32 + k0 + j]);
        *(bvec8*)(apg1 + (size_t)u * 8) = pk.v;
    }
}

// ---------------- kernel 1: xx = Wx·x as MFMA GEMM, interleaved bf16 out ----------------
__global__ __launch_bounds__(256) void k_xx_mfma(
        const unsigned short* __restrict__ xb, const unsigned short* __restrict__ apx,
        unsigned short* __restrict__ xxb) {
    int bid = blockIdx.x;
    int n = bid / 27, pc = bid % 27;
    int tid = threadIdx.x;
    int w = tid >> 6, lane = tid & 63;
    int ln = lane & 15, kgrp = lane >> 4;
    const bvec8* A = (const bvec8*)apx;
    bvec8 af[4][4];
    #pragma unroll
    for (int s = 0; s < 4; ++s)
        #pragma unroll
        for (int i = 0; i < 4; ++i)
            af[s][i] = A[(s * 16 + w * 4 + i) * 64 + lane];
    fvec4 acc[4][3];
    #pragma unroll
    for (int i = 0; i < 4; ++i)
        #pragma unroll
        for (int jn = 0; jn < 3; ++jn)
            acc[i][jn] = fvec4{0.f, 0.f, 0.f, 0.f};
    #pragma unroll
    for (int s = 0; s < 4; ++s) {
        #pragma unroll
        for (int jn = 0; jn < 3; ++jn) {
            int p = pc * 48 + jn * 16 + ln;
            bvec8 bfr = *(const bvec8*)(xb + ((size_t)(n * 16 + s * 4 + kgrp) * HW + p) * 8);
            #pragma unroll
            for (int i = 0; i < 4; ++i)
                acc[i][jn] = __builtin_amdgcn_mfma_f32_16x16x32_bf16(af[s][i], bfr, acc[i][jn], 0, 0, 0);
        }
    }
    #pragma unroll
    for (int i = 0; i < 4; ++i) {
        int co0 = (w * 4 + i) * 16 + kgrp * 4;
        int icb = co0 >> 3, sub = co0 & 7;
        #pragma unroll
        for (int jn = 0; jn < 3; ++jn) {
            int p = pc * 48 + jn * 16 + ln;
            union { unsigned short us[4]; unsigned long long u; } pk;
            #pragma unroll
            for (int r = 0; r < 4; ++r) pk.us[r] = f2bf(acc[i][jn][r]);
            *(unsigned long long*)(xxb + ((size_t)(n * 32 + icb) * HW + p) * 8 + sub) = pk.u;
        }
    }
}

// ---------------- kernel 2: MFMA grouped 3x3 conv -> qT, kT, vS (slot-permuted V) ----------------
// vS: [ng][c:32][1184] where within each 32-key tile, slot = ((kk&15)>>2)*8 + ((kk>>4)<<2) + (kk&3)
__global__ __launch_bounds__(384) void k_qkv_mfma(
        const unsigned short* __restrict__ xxb, const unsigned short* __restrict__ h0b,
        const unsigned short* __restrict__ apq,
        unsigned short* __restrict__ qT, unsigned short* __restrict__ kT,
        unsigned short* __restrict__ vS) {
    int bid = blockIdx.x;
    int n = bid / 72, rem = bid % 72;
    int g = rem / 9, yt = rem % 9;
    __shared__ bvec8 sm[1824];
    int tid = threadIdx.x;
    for (int u = tid; u < 1824; u += 384) {
        int col = u % 38; int t2 = u / 38;
        int icb = t2 % 8; int rr = t2 / 8;
        int y = yt * 4 - 1 + rr, cx = col - 1;
        bvec8 val = {0, 0, 0, 0, 0, 0, 0, 0};
        if (y >= 0 && y < 36 && cx >= 0 && cx < 36) {
            const unsigned short* src = (icb < 4)
                ? (xxb + ((size_t)(n * 32 + g * 4 + icb) * HW) * 8)
                : (h0b + ((size_t)(n * 32 + g * 4 + icb - 4) * HW) * 8);
            val = *(const bvec8*)(src + (size_t)(y * 36 + cx) * 8);
        }
        int s = rr * 38 + col;
        sm[s * 8 + (icb ^ (s & 7))] = val;
    }
    __syncthreads();
    int lane = tid & 63, w = tid >> 6;
    int mg = w % 3, nh = w / 3;
    int kgrp = lane >> 4;
    int nf0 = nh * 4;
    int sb[5], pl[5];
    #pragma unroll
    for (int jn = 0; jn < 5; ++jn) {
        int p = (nf0 + jn) * 16 + (lane & 15);
        pl[jn] = p;
        sb[jn] = (p / 36) * 38 + (p % 36);
    }
    fvec4 acc[2][5];
    #pragma unroll
    for (int i = 0; i < 2; ++i)
        #pragma unroll
        for (int jn = 0; jn < 5; ++jn)
            acc[i][jn] = fvec4{0.f, 0.f, 0.f, 0.f};
    const bvec8* ap = (const bvec8*)apq + (size_t)g * 6912 + mg * 128 + lane;
    for (int s = 0; s < 18; ++s) {
        int kyx = s >> 1, icb = s & 1;
        int ky = kyx / 3, kx = kyx % 3;
        bvec8 a0 = ap[0], a1 = ap[64];
        ap += 384;
        int soff = ky * 38 + kx;
        int ib = icb * 4 + kgrp;
        #pragma unroll
        for (int jn = 0; jn < 5; ++jn) {
            int slot = sb[jn] + soff;
            bvec8 bfr = sm[slot * 8 + (ib ^ (slot & 7))];
            acc[0][jn] = __builtin_amdgcn_mfma_f32_16x16x32_bf16(a0, bfr, acc[0][jn], 0, 0, 0);
            acc[1][jn] = __builtin_amdgcn_mfma_f32_16x16x32_bf16(a1, bfr, acc[1][jn], 0, 0, 0);
        }
    }
    int ngb = n * 8 + g;
    unsigned short* qTg = qT + (size_t)ngb * 41472;
    unsigned short* kTg = kT + (size_t)ngb * 36992;
    unsigned short* vSg = vS + (size_t)ngb * 37888;
    #pragma unroll
    for (int i = 0; i < 2; ++i) {
        int mf = mg * 2 + i;
        int m0 = mf * 16 + kgrp * 4;
        int conv = m0 >> 5, c0 = m0 & 31;
        #pragma unroll
        for (int jn = 0; jn < 5; ++jn) {
            int gp = yt * 144 + pl[jn];
            int py = gp / 36, px = gp % 36;
            if (conv == 0) {
                union { unsigned short us[4]; unsigned long long u; } pk;
                #pragma unroll
                for (int r = 0; r < 4; ++r) pk.us[r] = f2bf(acc[i][jn][r]);
                *(unsigned long long*)(qTg + (size_t)gp * 32 + c0) = pk.u;
            } else if (py >= 1 && py <= 34 && px >= 1 && px <= 34) {
                int dpix = (py - 1) * 34 + (px - 1);
                if (conv == 1) {
                    union { unsigned short us[4]; unsigned long long u; } pk;
                    #pragma unroll
                    for (int r = 0; r < 4; ++r) pk.us[r] = f2bf(acc[i][jn][r]);
                    *(unsigned long long*)(kTg + (size_t)dpix * 32 + c0) = pk.u;
                } else {
                    int tt = dpix >> 5, kk = dpix & 31;
                    int slot = ((kk & 15) >> 2) * 8 + ((kk >> 4) << 2) + (kk & 3);
                    int idx = tt * 32 + slot;
                    #pragma unroll
                    for (int r = 0; r < 4; ++r)
                        vSg[(size_t)(c0 + r) * 1184 + idx] = f2bf(acc[i][jn][r]);
                }
            }
        }
    }
}

// ---------------- kernel 3: MFMA flash attention, zero-shuffle PV, no LDS ----------------
// Key-permutation invariance: each lane's own cvt_pk dwords ARE its PV B-operand;
// V was stored slot-permuted to match. Wq carries tau*log2e -> p = 2^s.
__global__ __launch_bounds__(256) void k_attn_mfma(
        const unsigned short* __restrict__ qT, const unsigned short* __restrict__ kT,
        const unsigned short* __restrict__ vS, unsigned short* __restrict__ ab) {
    int bid = blockIdx.x;
    int ng = bid / 21, bt = bid % 21;
    int tid = threadIdx.x;
    int w = tid >> 6, l = tid & 63;
    int qblk = bt * 4 + w;
    bool qvalid = qblk < 81;
    int qb = qvalid ? qblk : 80;
    int ln = l & 15, g = l >> 4;
    const unsigned short* qTg = qT + (size_t)ng * 41472;
    const unsigned short* kTg = kT + (size_t)ng * 36992;
    const unsigned short* vSg = vS + (size_t)ng * 37888;
    bvec8 qf = *(const bvec8*)(qTg + (size_t)(qb * 16 + ln) * 32 + g * 8);
    const unsigned short* kp = kTg + ln * 32 + g * 8;            // + t*1024 (+512 hi keys)
    const unsigned short* vp = vSg + (size_t)ln * 1184 + g * 8;  // + t*32 (+18944 for ch 16..31)
    fvec4 acc0 = {0.f, 0.f, 0.f, 0.f}, acc1 = {0.f, 0.f, 0.f, 0.f};
    fvec4 zero = {0.f, 0.f, 0.f, 0.f};
    float lp = 0.f;
    bvec8 ka0 = *(const bvec8*)(kp);
    bvec8 ka1 = *(const bvec8*)(kp + 512);
    bvec8 va0 = *(const bvec8*)(vp);
    bvec8 va1 = *(const bvec8*)(vp + 18944);
    #pragma unroll 2
    for (int t = 0; t < 36; ++t) {
        int tn = (t < 35) ? t + 1 : 35;
        bvec8 nk0 = *(const bvec8*)(kp + tn * 1024);
        bvec8 nk1 = *(const bvec8*)(kp + tn * 1024 + 512);
        bvec8 nv0 = *(const bvec8*)(vp + tn * 32);
        bvec8 nv1 = *(const bvec8*)(vp + tn * 32 + 18944);
        fvec4 s0 = __builtin_amdgcn_mfma_f32_16x16x32_bf16(ka0, qf, zero, 0, 0, 0);
        fvec4 s1 = __builtin_amdgcn_mfma_f32_16x16x32_bf16(ka1, qf, zero, 0, 0, 0);
        float p[8];
        #pragma unroll
        for (int r = 0; r < 4; ++r) {
            p[r]     = exp2a(s0[r]);
            p[4 + r] = exp2a(s1[r]);
        }
        lp += ((p[0] + p[1]) + (p[2] + p[3])) + ((p[4] + p[5]) + (p[6] + p[7]));
        union { unsigned int ui[4]; bvec8 v; } pB;
        pB.ui[0] = cvtpk_bf16(p[0], p[1]);
        pB.ui[1] = cvtpk_bf16(p[2], p[3]);
        pB.ui[2] = cvtpk_bf16(p[4], p[5]);
        pB.ui[3] = cvtpk_bf16(p[6], p[7]);
        acc0 = __builtin_amdgcn_mfma_f32_16x16x32_bf16(va0, pB.v, acc0, 0, 0, 0);
        acc1 = __builtin_amdgcn_mfma_f32_16x16x32_bf16(va1, pB.v, acc1, 0, 0, 0);
        ka0 = nk0; ka1 = nk1; va0 = nv0; va1 = nv1;
    }
    {   // tail: keys 1152..1155 (lane's own A-dwords valid only for g==0)
        bvec8 tk = *(const bvec8*)(kTg + (size_t)min(1152 + ln, 1155) * 32 + g * 8);
        fvec4 s0 = __builtin_amdgcn_mfma_f32_16x16x32_bf16(tk, qf, zero, 0, 0, 0);
        float p[4];
        #pragma unroll
        for (int r = 0; r < 4; ++r)
            p[r] = (g == 0) ? exp2a(s0[r]) : 0.f;
        lp += (p[0] + p[1]) + (p[2] + p[3]);
        union { unsigned int ui[4]; bvec8 v; } pB;
        pB.ui[0] = cvtpk_bf16(p[0], p[1]);
        pB.ui[1] = cvtpk_bf16(p[2], p[3]);
        pB.ui[2] = 0u;
        pB.ui[3] = 0u;
        bvec8 tv0 = *(const bvec8*)(vp + 36 * 32);
        bvec8 tv1 = *(const bvec8*)(vp + 36 * 32 + 18944);
        acc0 = __builtin_amdgcn_mfma_f32_16x16x32_bf16(tv0, pB.v, acc0, 0, 0, 0);
        acc1 = __builtin_amdgcn_mfma_f32_16x16x32_bf16(tv1, pB.v, acc1, 0, 0, 0);
    }
    float lt = lp;
    lt += __shfl_xor(lt, 16, 64);
    lt += __shfl_xor(lt, 32, 64);
    float inv = 1.f / lt;
    if (qvalid) {
        int qpos = qblk * 16 + ln;
        unsigned short* ag = ab + (size_t)ng * 41472;
        int sub = (g & 1) * 4;
        union { unsigned short us[4]; unsigned long long u; } pk0, pk1;
        #pragma unroll
        for (int r = 0; r < 4; ++r) {
            pk0.us[r] = f2bf(acc0[r] * inv);
            pk1.us[r] = f2bf(acc1[r] * inv);
        }
        *(unsigned long long*)(ag + ((size_t)(g >> 1) * HW + qpos) * 8 + sub)       = pk0.u;
        *(unsigned long long*)(ag + ((size_t)(2 + (g >> 1)) * HW + qpos) * 8 + sub) = pk1.u;
    }
}

// ---------------- kernel 4: MFMA gates + LSTM combine ----------------
__global__ __launch_bounds__(256) void k_gates_mfma(
        const unsigned short* __restrict__ xxb, const unsigned short* __restrict__ h0b,
        const float* __restrict__ c0, const unsigned short* __restrict__ ab,
        const unsigned short* __restrict__ apg2, const unsigned short* __restrict__ apg1,
        const float* __restrict__ bi, const float* __restrict__ bf_,
        const float* __restrict__ bg, const float* __restrict__ bo,
        float* __restrict__ out) {
    int bid = blockIdx.x;
    int n = bid / 72, rem = bid % 72;
    int g = rem / 9, yt = rem % 9;
    __shared__ bvec8 smx[1824];
    __shared__ bvec8 sma[576];
    int tid = threadIdx.x;
    for (int u = tid; u < 1824; u += 256) {
        int col = u % 38; int t2 = u / 38;
        int icb = t2 % 8; int rr = t2 / 8;
        int y = yt * 4 - 1 + rr, cx = col - 1;
        bvec8 val = {0, 0, 0, 0, 0, 0, 0, 0};
        if (y >= 0 && y < 36 && cx >= 0 && cx < 36) {
            const unsigned short* src = (icb < 4)
                ? (xxb + ((size_t)(n * 32 + g * 4 + icb) * HW) * 8)
                : (h0b + ((size_t)(n * 32 + g * 4 + icb - 4) * HW) * 8);
            val = *(const bvec8*)(src + (size_t)(y * 36 + cx) * 8);
        }
        int s = rr * 38 + col;
        smx[s * 8 + (icb ^ (s & 7))] = val;
    }
    int ngb = n * 8 + g;
    for (int u = tid; u < 576; u += 256) {
        int p = u % 144, cb = u / 144;
        int gp = yt * 144 + p;
        bvec8 val = *(const bvec8*)(ab + ((size_t)(ngb * 4 + cb) * HW + gp) * 8);
        sma[p * 4 + (cb ^ (p & 3))] = val;
    }
    __syncthreads();
    int lane = tid & 63, w = tid >> 6;
    int b = w & 1, nh = w >> 1;
    int kgrp = lane >> 4, nf0 = nh * 4;
    int sb[5], pl[5];
    #pragma unroll
    for (int jn = 0; jn < 5; ++jn) {
        int p = (nf0 + jn) * 16 + (lane & 15);
        pl[jn] = p;
        sb[jn] = (p / 36) * 38 + (p % 36);
    }
    fvec4 acc[4][5];
    #pragma unroll
    for (int i = 0; i < 4; ++i)
        #pragma unroll
        for (int jn = 0; jn < 5; ++jn)
            acc[i][jn] = fvec4{0.f, 0.f, 0.f, 0.f};
    const bvec8* ap = (const bvec8*)apg2 + ((size_t)g * 144 + b) * 64 + lane;
    for (int s = 0; s < 18; ++s) {
        int kyx = s >> 1, icb = s & 1;
        int ky = kyx / 3, kx = kyx % 3;
        bvec8 a0 = ap[0], a1 = ap[128], a2 = ap[256], a3 = ap[384];
        ap += 512;
        int soff = ky * 38 + kx;
        int ib = icb * 4 + kgrp;
        #pragma unroll
        for (int jn = 0; jn < 5; ++jn) {
            int slot = sb[jn] + soff;
            bvec8 bfr = smx[slot * 8 + (ib ^ (slot & 7))];
            acc[0][jn] = __builtin_amdgcn_mfma_f32_16x16x32_bf16(a0, bfr, acc[0][jn], 0, 0, 0);
            acc[1][jn] = __builtin_amdgcn_mfma_f32_16x16x32_bf16(a1, bfr, acc[1][jn], 0, 0, 0);
            acc[2][jn] = __builtin_amdgcn_mfma_f32_16x16x32_bf16(a2, bfr, acc[2][jn], 0, 0, 0);
            acc[3][jn] = __builtin_amdgcn_mfma_f32_16x16x32_bf16(a3, bfr, acc[3][jn], 0, 0, 0);
        }
    }
    {
        const bvec8* ap1 = (const bvec8*)apg1 + ((size_t)g * 8 + b) * 64 + lane;
        bvec8 a0 = ap1[0], a1 = ap1[128], a2 = ap1[256], a3 = ap1[384];
        #pragma unroll
        for (int jn = 0; jn < 5; ++jn) {
            int p = pl[jn];
            bvec8 bfr = sma[p * 4 + (kgrp ^ (p & 3))];
            acc[0][jn] = __builtin_amdgcn_mfma_f32_16x16x32_bf16(a0, bfr, acc[0][jn], 0, 0, 0);
            acc[1][jn] = __builtin_amdgcn_mfma_f32_16x16x32_bf16(a1, bfr, acc[1][jn], 0, 0, 0);
            acc[2][jn] = __builtin_amdgcn_mfma_f32_16x16x32_bf16(a2, bfr, acc[2][jn], 0, 0, 0);
            acc[3][jn] = __builtin_amdgcn_mfma_f32_16x16x32_bf16(a3, bfr, acc[3][jn], 0, 0, 0);
        }
    }
    #pragma unroll
    for (int jn = 0; jn < 5; ++jn) {
        int gp = yt * 144 + pl[jn];
        #pragma unroll
        for (int r = 0; r < 4; ++r) {
            int cl = b * 16 + kgrp * 4 + r;
            int co = g * 32 + cl;
            float ip   = acc[0][jn][r] + bi[co];
            float fp   = acc[1][jn][r] + bf_[co];
            float gpre = acc[2][jn][r] + bg[co];
            float op   = acc[3][jn][r] + bo[co];
            float iv = sigmoidf_(ip), fv = sigmoidf_(fp);
            float gv = tanhf_(gpre), ov = sigmoidf_(op);
            float cv = fmaf(fv, c0[(size_t)(n * CC + co) * HW + gp], iv * gv);
            out[(size_t)(n * CC + co) * HW + gp] = ov * tanhf_(cv);
        }
    }
}

extern "C" void kernel_launch(void* const* d_in, const int* in_sizes, int n_in,
                              void* d_out, int out_size, void* d_ws, size_t ws_size,
                              hipStream_t stream) {
    const float* x   = (const float*)d_in[0];
    const float* h0  = (const float*)d_in[1];
    const float* c0  = (const float*)d_in[2];
    const float* Wx  = (const float*)d_in[3];
    const float* Wq  = (const float*)d_in[4];
    const float* Wk  = (const float*)d_in[5];
    const float* Wv  = (const float*)d_in[6];
    const float* Wi1 = (const float*)d_in[7];
    const float* Wi2 = (const float*)d_in[8];
    const float* bi  = (const float*)d_in[9];
    const float* Wf1 = (const float*)d_in[10];
    const float* Wf2 = (const float*)d_in[11];
    const float* bf  = (const float*)d_in[12];
    const float* Wg1 = (const float*)d_in[13];
    const float* Wg2 = (const float*)d_in[14];
    const float* bg  = (const float*)d_in[15];
    const float* Wo1 = (const float*)d_in[16];
    const float* Wo2 = (const float*)d_in[17];
    const float* bo  = (const float*)d_in[18];
    const float* tau = (const float*)d_in[19];

    unsigned short* ws  = (unsigned short*)d_ws;
    unsigned short* xb   = ws;                   // 1,327,104
    unsigned short* h0b  = xb   + 1327104;       // 2,654,208
    unsigned short* xxb  = h0b  + 2654208;       // 2,654,208
    unsigned short* ab   = xxb  + 2654208;       // 2,654,208
    unsigned short* qT   = ab   + 2654208;       // 2,654,208
    unsigned short* kT   = qT   + 2654208;       // 2,367,488
    unsigned short* vS   = kT   + 2367488;       // 2,424,832 (64 x 32 x 1184)
    unsigned short* apx  = vS   + 2424832;       // 32,768
    unsigned short* apq  = apx  + 32768;         // 442,368
    unsigned short* apg2 = apq  + 442368;        // 589,824
    unsigned short* apg1 = apg2 + 589824;        // 32,768
    float* out = (float*)d_out;

    hipLaunchKernelGGL(k_prep, dim3(920), dim3(256), 0, stream,
                       x, h0, Wx, Wq, Wk, Wv, tau,
                       Wi2, Wf2, Wg2, Wo2, Wi1, Wf1, Wg1, Wo1,
                       xb, h0b, apx, apq, apg2, apg1);
    hipLaunchKernelGGL(k_xx_mfma,   dim3(216),  dim3(256), 0, stream, xb, apx, xxb);
    hipLaunchKernelGGL(k_qkv_mfma,  dim3(576),  dim3(384), 0, stream, xxb, h0b, apq, qT, kT, vS);
    hipLaunchKernelGGL(k_attn_mfma, dim3(1344), dim3(256), 0, stream, qT, kT, vS, ab);
    hipLaunchKernelGGL(k_gates_mfma,dim3(576),  dim3(256), 0, stream, xxb, h0b, c0, ab,
                       apg2, apg1, bi, bf, bg, bo, out);
}

// Round 8
// 131.451 us; speedup vs baseline: 1.0254x; 1.0254x over previous
//
#include <hip/hip_runtime.h>
#include <math.h>

#define NN  8
#define CIN 128
#define HW  1296
#define CC  256
#define DDS 1156

typedef __attribute__((ext_vector_type(8))) short bvec8;
typedef __attribute__((ext_vector_type(4))) float fvec4;

__device__ __forceinline__ float sigmoidf_(float x) {
    return 1.f / (1.f + __expf(-x));
}
__device__ __forceinline__ float tanhf_(float x) {
    float xa = fminf(fmaxf(x, -15.f), 15.f);
    float e = __expf(2.f * xa);
    return (e - 1.f) / (e + 1.f);
}
__device__ __forceinline__ unsigned short f2bf(float f) {
    unsigned int u = __float_as_uint(f);
    u = (u + 0x7FFFu + ((u >> 16) & 1u)) >> 16;
    return (unsigned short)u;
}
__device__ __forceinline__ unsigned int cvtpk_bf16(float a, float b) {
    unsigned int r;
    asm("v_cvt_pk_bf16_f32 %0, %1, %2" : "=v"(r) : "v"(a), "v"(b));
    return r;   // lo16 = bf16(a), hi16 = bf16(b), RTNE
}
__device__ __forceinline__ float exp2a(float x) {   // 2^x, single v_exp_f32
    float r;
    asm("v_exp_f32 %0, %1" : "=v"(r) : "v"(x));
    return r;
}

// ---------------- kernel 0: prep ----------------
__global__ __launch_bounds__(256) void k_prep(
        const float* __restrict__ x, const float* __restrict__ h0,
        const float* __restrict__ Wx,
        const float* __restrict__ Wq, const float* __restrict__ Wk,
        const float* __restrict__ Wv, const float* __restrict__ tau,
        const float* __restrict__ Wi2, const float* __restrict__ Wf2,
        const float* __restrict__ Wg2, const float* __restrict__ Wo2,
        const float* __restrict__ Wi1, const float* __restrict__ Wf1,
        const float* __restrict__ Wg1, const float* __restrict__ Wo1,
        unsigned short* __restrict__ xb, unsigned short* __restrict__ h0b,
        unsigned short* __restrict__ apx, unsigned short* __restrict__ apq,
        unsigned short* __restrict__ apg2, unsigned short* __restrict__ apg1) {
    __shared__ float tr[10400];          // 8 ch x stride 1300 (bank-clean)
    int bid = blockIdx.x;
    int tid = threadIdx.x;
    if (bid < 384) {
        int n = bid / 48, cb = bid % 48;
        const float* src = (cb < 16) ? x  + (size_t)(n * CIN + cb * 8) * HW
                                     : h0 + (size_t)(n * CC + (cb - 16) * 8) * HW;
        unsigned short* dst = (cb < 16) ? xb  + ((size_t)(n * 16 + cb) * HW) * 8
                                        : h0b + ((size_t)(n * 32 + (cb - 16)) * HW) * 8;
        #pragma unroll
        for (int c = 0; c < 8; ++c)
            for (int p4 = tid; p4 < 324; p4 += 256) {
                float4 v = ((const float4*)(src + (size_t)c * HW))[p4];
                *(float4*)&tr[c * 1300 + p4 * 4] = v;
            }
        __syncthreads();
        for (int p = tid; p < 1296; p += 256) {
            union { unsigned short us[8]; bvec8 v; } pk;
            #pragma unroll
            for (int c = 0; c < 8; ++c) pk.us[c] = f2bf(tr[c * 1300 + p]);
            *(bvec8*)(dst + (size_t)p * 8) = pk.v;
        }
        return;
    }
    int t = (bid - 384) * 256 + tid;
    union { unsigned short us[8]; bvec8 v; } pk;
    if (t < 55296) {                        // apq (Wq scaled by tau*log2e)
        int u = t;
        int lane = u & 63;
        int t2 = u >> 6;
        int mf = t2 % 6, t3 = t2 / 6;
        int s = t3 % 18, g = t3 / 18;
        int kyx = s >> 1, icb = s & 1;
        int ky = kyx / 3, kx = kyx % 3;
        int m = mf * 16 + (lane & 15);
        int conv = m >> 5, cl = m & 31, co = g * 32 + cl;
        int ic0 = icb * 32 + (lane >> 4) * 8;
        const float* W = (conv == 0) ? Wq : (conv == 1 ? Wk : Wv);
        float scale = (conv == 0) ? tau[g] * 1.4426950408889634f : 1.f;
        #pragma unroll
        for (int j = 0; j < 8; ++j)
            pk.us[j] = f2bf(W[((co * 64 + ic0 + j) * 3 + ky) * 3 + kx] * scale);
        *(bvec8*)(apq + (size_t)u * 8) = pk.v;
    } else if (t < 59392) {                 // apx
        int u = t - 55296;
        int lane = u & 63;
        int t2 = u >> 6;
        int mf = t2 % 16, s = t2 / 16;
        int co = mf * 16 + (lane & 15);
        int k0 = s * 32 + (lane >> 4) * 8;
        #pragma unroll
        for (int j = 0; j < 8; ++j)
            pk.us[j] = f2bf(Wx[co * CIN + k0 + j]);
        *(bvec8*)(apx + (size_t)u * 8) = pk.v;
    } else if (t < 133120) {                // apg2
        int u = t - 59392;
        int lane = u & 63;
        int t2 = u >> 6;
        int mf = t2 % 8, t3 = t2 / 8;
        int s = t3 % 18, g = t3 / 18;
        int kyx = s >> 1, icb = s & 1;
        int ky = kyx / 3, kx = kyx % 3;
        int m = mf * 16 + (lane & 15);
        int gate = m >> 5, cl = m & 31, co = g * 32 + cl;
        int ic0 = icb * 32 + (lane >> 4) * 8;
        const float* W = (gate == 0) ? Wi2 : (gate == 1 ? Wf2 : (gate == 2 ? Wg2 : Wo2));
        #pragma unroll
        for (int j = 0; j < 8; ++j)
            pk.us[j] = f2bf(W[((co * 64 + ic0 + j) * 3 + ky) * 3 + kx]);
        *(bvec8*)(apg2 + (size_t)u * 8) = pk.v;
    } else if (t < 137216) {                // apg1
        int u = t - 133120;
        int lane = u & 63;
        int t2 = u >> 6;
        int mf = t2 % 8, g = t2 / 8;
        int m = mf * 16 + (lane & 15);
        int gate = m >> 5, cl = m & 31, co = g * 32 + cl;
        int k0 = (lane >> 4) * 8;
        const float* W = (gate == 0) ? Wi1 : (gate == 1 ? Wf1 : (gate == 2 ? Wg1 : Wo1));
        #pragma unroll
        for (int j = 0; j < 8; ++j)
            pk.us[j] = f2bf(W[co * 32 + k0 + j]);
        *(bvec8*)(apg1 + (size_t)u * 8) = pk.v;
    }
}

// ---------------- kernel 1: xx = Wx·x as MFMA GEMM, interleaved bf16 out ----------------
__global__ __launch_bounds__(256) void k_xx_mfma(
        const unsigned short* __restrict__ xb, const unsigned short* __restrict__ apx,
        unsigned short* __restrict__ xxb) {
    int bid = blockIdx.x;
    int n = bid / 27, pc = bid % 27;
    int tid = threadIdx.x;
    int w = tid >> 6, lane = tid & 63;
    int ln = lane & 15, kgrp = lane >> 4;
    const bvec8* A = (const bvec8*)apx;
    bvec8 af[4][4];
    #pragma unroll
    for (int s = 0; s < 4; ++s)
        #pragma unroll
        for (int i = 0; i < 4; ++i)
            af[s][i] = A[(s * 16 + w * 4 + i) * 64 + lane];
    fvec4 acc[4][3];
    #pragma unroll
    for (int i = 0; i < 4; ++i)
        #pragma unroll
        for (int jn = 0; jn < 3; ++jn)
            acc[i][jn] = fvec4{0.f, 0.f, 0.f, 0.f};
    #pragma unroll
    for (int s = 0; s < 4; ++s) {
        #pragma unroll
        for (int jn = 0; jn < 3; ++jn) {
            int p = pc * 48 + jn * 16 + ln;
            bvec8 bfr = *(const bvec8*)(xb + ((size_t)(n * 16 + s * 4 + kgrp) * HW + p) * 8);
            #pragma unroll
            for (int i = 0; i < 4; ++i)
                acc[i][jn] = __builtin_amdgcn_mfma_f32_16x16x32_bf16(af[s][i], bfr, acc[i][jn], 0, 0, 0);
        }
    }
    #pragma unroll
    for (int i = 0; i < 4; ++i) {
        int co0 = (w * 4 + i) * 16 + kgrp * 4;
        int icb = co0 >> 3, sub = co0 & 7;
        #pragma unroll
        for (int jn = 0; jn < 3; ++jn) {
            int p = pc * 48 + jn * 16 + ln;
            union { unsigned short us[4]; unsigned long long u; } pk;
            #pragma unroll
            for (int r = 0; r < 4; ++r) pk.us[r] = f2bf(acc[i][jn][r]);
            *(unsigned long long*)(xxb + ((size_t)(n * 32 + icb) * HW + p) * 8 + sub) = pk.u;
        }
    }
}

// ---------------- kernel 2: MFMA grouped 3x3 conv -> qT, kT, vS (slot-permuted V) ----------------
__global__ __launch_bounds__(384) void k_qkv_mfma(
        const unsigned short* __restrict__ xxb, const unsigned short* __restrict__ h0b,
        const unsigned short* __restrict__ apq,
        unsigned short* __restrict__ qT, unsigned short* __restrict__ kT,
        unsigned short* __restrict__ vS) {
    int bid = blockIdx.x;
    int n = bid / 72, rem = bid % 72;
    int g = rem / 9, yt = rem % 9;
    __shared__ bvec8 sm[1824];
    int tid = threadIdx.x;
    for (int u = tid; u < 1824; u += 384) {
        int col = u % 38; int t2 = u / 38;
        int icb = t2 % 8; int rr = t2 / 8;
        int y = yt * 4 - 1 + rr, cx = col - 1;
        bvec8 val = {0, 0, 0, 0, 0, 0, 0, 0};
        if (y >= 0 && y < 36 && cx >= 0 && cx < 36) {
            const unsigned short* src = (icb < 4)
                ? (xxb + ((size_t)(n * 32 + g * 4 + icb) * HW) * 8)
                : (h0b + ((size_t)(n * 32 + g * 4 + icb - 4) * HW) * 8);
            val = *(const bvec8*)(src + (size_t)(y * 36 + cx) * 8);
        }
        int s = rr * 38 + col;
        sm[s * 8 + (icb ^ (s & 7))] = val;
    }
    __syncthreads();
    int lane = tid & 63, w = tid >> 6;
    int mg = w % 3, nh = w / 3;
    int kgrp = lane >> 4;
    int nf0 = nh * 4;
    int sb[5], pl[5];
    #pragma unroll
    for (int jn = 0; jn < 5; ++jn) {
        int p = (nf0 + jn) * 16 + (lane & 15);
        pl[jn] = p;
        sb[jn] = (p / 36) * 38 + (p % 36);
    }
    fvec4 acc[2][5];
    #pragma unroll
    for (int i = 0; i < 2; ++i)
        #pragma unroll
        for (int jn = 0; jn < 5; ++jn)
            acc[i][jn] = fvec4{0.f, 0.f, 0.f, 0.f};
    const bvec8* ap = (const bvec8*)apq + (size_t)g * 6912 + mg * 128 + lane;
    for (int s = 0; s < 18; ++s) {
        int kyx = s >> 1, icb = s & 1;
        int ky = kyx / 3, kx = kyx % 3;
        bvec8 a0 = ap[0], a1 = ap[64];
        ap += 384;
        int soff = ky * 38 + kx;
        int ib = icb * 4 + kgrp;
        #pragma unroll
        for (int jn = 0; jn < 5; ++jn) {
            int slot = sb[jn] + soff;
            bvec8 bfr = sm[slot * 8 + (ib ^ (slot & 7))];
            acc[0][jn] = __builtin_amdgcn_mfma_f32_16x16x32_bf16(a0, bfr, acc[0][jn], 0, 0, 0);
            acc[1][jn] = __builtin_amdgcn_mfma_f32_16x16x32_bf16(a1, bfr, acc[1][jn], 0, 0, 0);
        }
    }
    int ngb = n * 8 + g;
    unsigned short* qTg = qT + (size_t)ngb * 41472;
    unsigned short* kTg = kT + (size_t)ngb * 36992;
    unsigned short* vSg = vS + (size_t)ngb * 37888;
    #pragma unroll
    for (int i = 0; i < 2; ++i) {
        int mf = mg * 2 + i;
        int m0 = mf * 16 + kgrp * 4;
        int conv = m0 >> 5, c0 = m0 & 31;
        #pragma unroll
        for (int jn = 0; jn < 5; ++jn) {
            int gp = yt * 144 + pl[jn];
            int py = gp / 36, px = gp % 36;
            if (conv == 0) {
                union { unsigned short us[4]; unsigned long long u; } pk;
                #pragma unroll
                for (int r = 0; r < 4; ++r) pk.us[r] = f2bf(acc[i][jn][r]);
                *(unsigned long long*)(qTg + (size_t)gp * 32 + c0) = pk.u;
            } else if (py >= 1 && py <= 34 && px >= 1 && px <= 34) {
                int dpix = (py - 1) * 34 + (px - 1);
                if (conv == 1) {
                    union { unsigned short us[4]; unsigned long long u; } pk;
                    #pragma unroll
                    for (int r = 0; r < 4; ++r) pk.us[r] = f2bf(acc[i][jn][r]);
                    *(unsigned long long*)(kTg + (size_t)dpix * 32 + c0) = pk.u;
                } else {
                    int tt = dpix >> 5, kk = dpix & 31;
                    int slot = ((kk & 15) >> 2) * 8 + ((kk >> 4) << 2) + (kk & 3);
                    int idx = tt * 32 + slot;
                    #pragma unroll
                    for (int r = 0; r < 4; ++r)
                        vSg[(size_t)(c0 + r) * 1184 + idx] = f2bf(acc[i][jn][r]);
                }
            }
        }
    }
}

// ---------------- kernel 3: MFMA flash attention, depth-3 pipeline + XCD swizzle ----------------
#define ATTN_LOAD(ph, tt) \
    kb0##ph = *(const bvec8*)(kp + (tt) * 1024); \
    kb1##ph = *(const bvec8*)(kp + (tt) * 1024 + 512); \
    vb0##ph = *(const bvec8*)(vp + (tt) * 32); \
    vb1##ph = *(const bvec8*)(vp + (tt) * 32 + 18944);

#define ATTN_COMPUTE(ph) { \
    fvec4 s0 = __builtin_amdgcn_mfma_f32_16x16x32_bf16(kb0##ph, qf, zero, 0, 0, 0); \
    fvec4 s1 = __builtin_amdgcn_mfma_f32_16x16x32_bf16(kb1##ph, qf, zero, 0, 0, 0); \
    float p0 = exp2a(s0[0]), p1 = exp2a(s0[1]), p2 = exp2a(s0[2]), p3 = exp2a(s0[3]); \
    float p4 = exp2a(s1[0]), p5 = exp2a(s1[1]), p6 = exp2a(s1[2]), p7 = exp2a(s1[3]); \
    lp += ((p0 + p1) + (p2 + p3)) + ((p4 + p5) + (p6 + p7)); \
    union { unsigned int ui[4]; bvec8 v; } pB; \
    pB.ui[0] = cvtpk_bf16(p0, p1); \
    pB.ui[1] = cvtpk_bf16(p2, p3); \
    pB.ui[2] = cvtpk_bf16(p4, p5); \
    pB.ui[3] = cvtpk_bf16(p6, p7); \
    acc0 = __builtin_amdgcn_mfma_f32_16x16x32_bf16(vb0##ph, pB.v, acc0, 0, 0, 0); \
    acc1 = __builtin_amdgcn_mfma_f32_16x16x32_bf16(vb1##ph, pB.v, acc1, 0, 0, 0); }

__global__ __launch_bounds__(256) void k_attn_mfma(
        const unsigned short* __restrict__ qT, const unsigned short* __restrict__ kT,
        const unsigned short* __restrict__ vS, unsigned short* __restrict__ ab) {
    int bid = blockIdx.x;
    // XCD-aware bijective swizzle: all 21 blocks of one ng land on one XCD
    int r8 = bid & 7, q8 = bid >> 3;
    int bt = q8 % 21, ng = r8 + 8 * (q8 / 21);
    int tid = threadIdx.x;
    int w = tid >> 6, l = tid & 63;
    int qblk = bt * 4 + w;
    bool qvalid = qblk < 81;
    int qb = qvalid ? qblk : 80;
    int ln = l & 15, g = l >> 4;
    const unsigned short* qTg = qT + (size_t)ng * 41472;
    const unsigned short* kTg = kT + (size_t)ng * 36992;
    const unsigned short* vSg = vS + (size_t)ng * 37888;
    bvec8 qf = *(const bvec8*)(qTg + (size_t)(qb * 16 + ln) * 32 + g * 8);
    const unsigned short* kp = kTg + ln * 32 + g * 8;            // + t*1024 (+512 hi keys)
    const unsigned short* vp = vSg + (size_t)ln * 1184 + g * 8;  // + t*32 (+18944 ch 16..31)
    fvec4 acc0 = {0.f, 0.f, 0.f, 0.f}, acc1 = {0.f, 0.f, 0.f, 0.f};
    fvec4 zero = {0.f, 0.f, 0.f, 0.f};
    float lp = 0.f;
    bvec8 kb00, kb10, vb00, vb10;
    bvec8 kb01, kb11, vb01, vb11;
    bvec8 kb02, kb12, vb02, vb12;
    // tail fragments (keys 1152..1155), loaded once
    bvec8 tk  = *(const bvec8*)(kTg + (size_t)min(1152 + ln, 1155) * 32 + g * 8);
    bvec8 tv0 = *(const bvec8*)(vp + 36 * 32);
    bvec8 tv1 = *(const bvec8*)(vp + 36 * 32 + 18944);
    ATTN_LOAD(0, 0)
    ATTN_LOAD(1, 1)
    ATTN_LOAD(2, 2)
    for (int tb = 0; tb < 33; tb += 3) {
        ATTN_COMPUTE(0) ATTN_LOAD(0, tb + 3)
        ATTN_COMPUTE(1) ATTN_LOAD(1, tb + 4)
        ATTN_COMPUTE(2) ATTN_LOAD(2, tb + 5)
    }
    ATTN_COMPUTE(0)
    ATTN_COMPUTE(1)
    ATTN_COMPUTE(2)
    {   // tail: keys 1152..1155 (lane's own A-dwords valid only for g==0)
        fvec4 s0 = __builtin_amdgcn_mfma_f32_16x16x32_bf16(tk, qf, zero, 0, 0, 0);
        float p0 = 0.f, p1 = 0.f, p2 = 0.f, p3 = 0.f;
        if (g == 0) {
            p0 = exp2a(s0[0]); p1 = exp2a(s0[1]);
            p2 = exp2a(s0[2]); p3 = exp2a(s0[3]);
        }
        lp += (p0 + p1) + (p2 + p3);
        union { unsigned int ui[4]; bvec8 v; } pB;
        pB.ui[0] = cvtpk_bf16(p0, p1);
        pB.ui[1] = cvtpk_bf16(p2, p3);
        pB.ui[2] = 0u;
        pB.ui[3] = 0u;
        acc0 = __builtin_amdgcn_mfma_f32_16x16x32_bf16(tv0, pB.v, acc0, 0, 0, 0);
        acc1 = __builtin_amdgcn_mfma_f32_16x16x32_bf16(tv1, pB.v, acc1, 0, 0, 0);
    }
    float lt = lp;
    lt += __shfl_xor(lt, 16, 64);
    lt += __shfl_xor(lt, 32, 64);
    float inv = 1.f / lt;
    if (qvalid) {
        int qpos = qblk * 16 + ln;
        unsigned short* ag = ab + (size_t)ng * 41472;
        int sub = (g & 1) * 4;
        union { unsigned short us[4]; unsigned long long u; } pk0, pk1;
        #pragma unroll
        for (int r = 0; r < 4; ++r) {
            pk0.us[r] = f2bf(acc0[r] * inv);
            pk1.us[r] = f2bf(acc1[r] * inv);
        }
        *(unsigned long long*)(ag + ((size_t)(g >> 1) * HW + qpos) * 8 + sub)       = pk0.u;
        *(unsigned long long*)(ag + ((size_t)(2 + (g >> 1)) * HW + qpos) * 8 + sub) = pk1.u;
    }
}

// ---------------- kernel 4: MFMA gates + LSTM combine ----------------
__global__ __launch_bounds__(256) void k_gates_mfma(
        const unsigned short* __restrict__ xxb, const unsigned short* __restrict__ h0b,
        const float* __restrict__ c0, const unsigned short* __restrict__ ab,
        const unsigned short* __restrict__ apg2, const unsigned short* __restrict__ apg1,
        const float* __restrict__ bi, const float* __restrict__ bf_,
        const float* __restrict__ bg, const float* __restrict__ bo,
        float* __restrict__ out) {
    int bid = blockIdx.x;
    int n = bid / 72, rem = bid % 72;
    int g = rem / 9, yt = rem % 9;
    __shared__ bvec8 smx[1824];
    __shared__ bvec8 sma[576];
    int tid = threadIdx.x;
    for (int u = tid; u < 1824; u += 256) {
        int col = u % 38; int t2 = u / 38;
        int icb = t2 % 8; int rr = t2 / 8;
        int y = yt * 4 - 1 + rr, cx = col - 1;
        bvec8 val = {0, 0, 0, 0, 0, 0, 0, 0};
        if (y >= 0 && y < 36 && cx >= 0 && cx < 36) {
            const unsigned short* src = (icb < 4)
                ? (xxb + ((size_t)(n * 32 + g * 4 + icb) * HW) * 8)
                : (h0b + ((size_t)(n * 32 + g * 4 + icb - 4) * HW) * 8);
            val = *(const bvec8*)(src + (size_t)(y * 36 + cx) * 8);
        }
        int s = rr * 38 + col;
        smx[s * 8 + (icb ^ (s & 7))] = val;
    }
    int ngb = n * 8 + g;
    for (int u = tid; u < 576; u += 256) {
        int p = u % 144, cb = u / 144;
        int gp = yt * 144 + p;
        bvec8 val = *(const bvec8*)(ab + ((size_t)(ngb * 4 + cb) * HW + gp) * 8);
        sma[p * 4 + (cb ^ (p & 3))] = val;
    }
    __syncthreads();
    int lane = tid & 63, w = tid >> 6;
    int b = w & 1, nh = w >> 1;
    int kgrp = lane >> 4, nf0 = nh * 4;
    int sb[5], pl[5];
    #pragma unroll
    for (int jn = 0; jn < 5; ++jn) {
        int p = (nf0 + jn) * 16 + (lane & 15);
        pl[jn] = p;
        sb[jn] = (p / 36) * 38 + (p % 36);
    }
    fvec4 acc[4][5];
    #pragma unroll
    for (int i = 0; i < 4; ++i)
        #pragma unroll
        for (int jn = 0; jn < 5; ++jn)
            acc[i][jn] = fvec4{0.f, 0.f, 0.f, 0.f};
    const bvec8* ap = (const bvec8*)apg2 + ((size_t)g * 144 + b) * 64 + lane;
    for (int s = 0; s < 18; ++s) {
        int kyx = s >> 1, icb = s & 1;
        int ky = kyx / 3, kx = kyx % 3;
        bvec8 a0 = ap[0], a1 = ap[128], a2 = ap[256], a3 = ap[384];
        ap += 512;
        int soff = ky * 38 + kx;
        int ib = icb * 4 + kgrp;
        #pragma unroll
        for (int jn = 0; jn < 5; ++jn) {
            int slot = sb[jn] + soff;
            bvec8 bfr = smx[slot * 8 + (ib ^ (slot & 7))];
            acc[0][jn] = __builtin_amdgcn_mfma_f32_16x16x32_bf16(a0, bfr, acc[0][jn], 0, 0, 0);
            acc[1][jn] = __builtin_amdgcn_mfma_f32_16x16x32_bf16(a1, bfr, acc[1][jn], 0, 0, 0);
            acc[2][jn] = __builtin_amdgcn_mfma_f32_16x16x32_bf16(a2, bfr, acc[2][jn], 0, 0, 0);
            acc[3][jn] = __builtin_amdgcn_mfma_f32_16x16x32_bf16(a3, bfr, acc[3][jn], 0, 0, 0);
        }
    }
    {
        const bvec8* ap1 = (const bvec8*)apg1 + ((size_t)g * 8 + b) * 64 + lane;
        bvec8 a0 = ap1[0], a1 = ap1[128], a2 = ap1[256], a3 = ap1[384];
        #pragma unroll
        for (int jn = 0; jn < 5; ++jn) {
            int p = pl[jn];
            bvec8 bfr = sma[p * 4 + (kgrp ^ (p & 3))];
            acc[0][jn] = __builtin_amdgcn_mfma_f32_16x16x32_bf16(a0, bfr, acc[0][jn], 0, 0, 0);
            acc[1][jn] = __builtin_amdgcn_mfma_f32_16x16x32_bf16(a1, bfr, acc[1][jn], 0, 0, 0);
            acc[2][jn] = __builtin_amdgcn_mfma_f32_16x16x32_bf16(a2, bfr, acc[2][jn], 0, 0, 0);
            acc[3][jn] = __builtin_amdgcn_mfma_f32_16x16x32_bf16(a3, bfr, acc[3][jn], 0, 0, 0);
        }
    }
    #pragma unroll
    for (int jn = 0; jn < 5; ++jn) {
        int gp = yt * 144 + pl[jn];
        #pragma unroll
        for (int r = 0; r < 4; ++r) {
            int cl = b * 16 + kgrp * 4 + r;
            int co = g * 32 + cl;
            float ip   = acc[0][jn][r] + bi[co];
            float fp   = acc[1][jn][r] + bf_[co];
            float gpre = acc[2][jn][r] + bg[co];
            float op   = acc[3][jn][r] + bo[co];
            float iv = sigmoidf_(ip), fv = sigmoidf_(fp);
            float gv = tanhf_(gpre), ov = sigmoidf_(op);
            float cv = fmaf(fv, c0[(size_t)(n * CC + co) * HW + gp], iv * gv);
            out[(size_t)(n * CC + co) * HW + gp] = ov * tanhf_(cv);
        }
    }
}

extern "C" void kernel_launch(void* const* d_in, const int* in_sizes, int n_in,
                              void* d_out, int out_size, void* d_ws, size_t ws_size,
                              hipStream_t stream) {
    const float* x   = (const float*)d_in[0];
    const float* h0  = (const float*)d_in[1];
    const float* c0  = (const float*)d_in[2];
    const float* Wx  = (const float*)d_in[3];
    const float* Wq  = (const float*)d_in[4];
    const float* Wk  = (const float*)d_in[5];
    const float* Wv  = (const float*)d_in[6];
    const float* Wi1 = (const float*)d_in[7];
    const float* Wi2 = (const float*)d_in[8];
    const float* bi  = (const float*)d_in[9];
    const float* Wf1 = (const float*)d_in[10];
    const float* Wf2 = (const float*)d_in[11];
    const float* bf  = (const float*)d_in[12];
    const float* Wg1 = (const float*)d_in[13];
    const float* Wg2 = (const float*)d_in[14];
    const float* bg  = (const float*)d_in[15];
    const float* Wo1 = (const float*)d_in[16];
    const float* Wo2 = (const float*)d_in[17];
    const float* bo  = (const float*)d_in[18];
    const float* tau = (const float*)d_in[19];

    unsigned short* ws  = (unsigned short*)d_ws;
    unsigned short* xb   = ws;                   // 1,327,104
    unsigned short* h0b  = xb   + 1327104;       // 2,654,208
    unsigned short* xxb  = h0b  + 2654208;       // 2,654,208
    unsigned short* ab   = xxb  + 2654208;       // 2,654,208
    unsigned short* qT   = ab   + 2654208;       // 2,654,208
    unsigned short* kT   = qT   + 2654208;       // 2,367,488
    unsigned short* vS   = kT   + 2367488;       // 2,424,832 (64 x 32 x 1184)
    unsigned short* apx  = vS   + 2424832;       // 32,768
    unsigned short* apq  = apx  + 32768;         // 442,368
    unsigned short* apg2 = apq  + 442368;        // 589,824
    unsigned short* apg1 = apg2 + 589824;        // 32,768
    float* out = (float*)d_out;

    hipLaunchKernelGGL(k_prep, dim3(920), dim3(256), 0, stream,
                       x, h0, Wx, Wq, Wk, Wv, tau,
                       Wi2, Wf2, Wg2, Wo2, Wi1, Wf1, Wg1, Wo1,
                       xb, h0b, apx, apq, apg2, apg1);
    hipLaunchKernelGGL(k_xx_mfma,   dim3(216),  dim3(256), 0, stream, xb, apx, xxb);
    hipLaunchKernelGGL(k_qkv_mfma,  dim3(576),  dim3(384), 0, stream, xxb, h0b, apq, qT, kT, vS);
    hipLaunchKernelGGL(k_attn_mfma, dim3(1344), dim3(256), 0, stream, qT, kT, vS, ab);
    hipLaunchKernelGGL(k_gates_mfma,dim3(576),  dim3(256), 0, stream, xxb, h0b, c0, ab,
                       apg2, apg1, bi, bf, bg, bo, out);
}

// Round 11
// 131.092 us; speedup vs baseline: 1.0283x; 1.0027x over previous
//
#include <hip/hip_runtime.h>
#include <math.h>

#define NN  8
#define CIN 128
#define HW  1296
#define CC  256
#define DDS 1156

typedef __attribute__((ext_vector_type(8))) short bvec8;
typedef __attribute__((ext_vector_type(4))) float fvec4;

__device__ __forceinline__ float sigmoidf_(float x) {
    return 1.f / (1.f + __expf(-x));
}
__device__ __forceinline__ float tanhf_(float x) {
    float xa = fminf(fmaxf(x, -15.f), 15.f);
    float e = __expf(2.f * xa);
    return (e - 1.f) / (e + 1.f);
}
__device__ __forceinline__ unsigned short f2bf(float f) {
    unsigned int u = __float_as_uint(f);
    u = (u + 0x7FFFu + ((u >> 16) & 1u)) >> 16;
    return (unsigned short)u;
}
__device__ __forceinline__ unsigned int cvtpk_bf16(float a, float b) {
    unsigned int r;
    asm("v_cvt_pk_bf16_f32 %0, %1, %2" : "=v"(r) : "v"(a), "v"(b));
    return r;   // lo16 = bf16(a), hi16 = bf16(b), RTNE
}
__device__ __forceinline__ float exp2a(float x) {   // 2^x, single v_exp_f32
    float r;
    asm("v_exp_f32 %0, %1" : "=v"(r) : "v"(x));
    return r;
}

// ---------------- kernel 0: prep ----------------
// blocks 0..383: LDS-transpose x/h0 -> interleaved bf16
// blocks 384..951: pack weights + ZERO vS tail tile (slots for keys 1152..1183)
__global__ __launch_bounds__(256) void k_prep(
        const float* __restrict__ x, const float* __restrict__ h0,
        const float* __restrict__ Wx,
        const float* __restrict__ Wq, const float* __restrict__ Wk,
        const float* __restrict__ Wv, const float* __restrict__ tau,
        const float* __restrict__ Wi2, const float* __restrict__ Wf2,
        const float* __restrict__ Wg2, const float* __restrict__ Wo2,
        const float* __restrict__ Wi1, const float* __restrict__ Wf1,
        const float* __restrict__ Wg1, const float* __restrict__ Wo1,
        unsigned short* __restrict__ xb, unsigned short* __restrict__ h0b,
        unsigned short* __restrict__ apx, unsigned short* __restrict__ apq,
        unsigned short* __restrict__ apg2, unsigned short* __restrict__ apg1,
        unsigned short* __restrict__ vS) {
    __shared__ float tr[10400];          // 8 ch x stride 1300 (bank-clean)
    int bid = blockIdx.x;
    int tid = threadIdx.x;
    if (bid < 384) {
        int n = bid / 48, cb = bid % 48;
        const float* src = (cb < 16) ? x  + (size_t)(n * CIN + cb * 8) * HW
                                     : h0 + (size_t)(n * CC + (cb - 16) * 8) * HW;
        unsigned short* dst = (cb < 16) ? xb  + ((size_t)(n * 16 + cb) * HW) * 8
                                        : h0b + ((size_t)(n * 32 + (cb - 16)) * HW) * 8;
        #pragma unroll
        for (int c = 0; c < 8; ++c)
            for (int p4 = tid; p4 < 324; p4 += 256) {
                float4 v = ((const float4*)(src + (size_t)c * HW))[p4];
                *(float4*)&tr[c * 1300 + p4 * 4] = v;
            }
        __syncthreads();
        for (int p = tid; p < 1296; p += 256) {
            union { unsigned short us[8]; bvec8 v; } pk;
            #pragma unroll
            for (int c = 0; c < 8; ++c) pk.us[c] = f2bf(tr[c * 1300 + p]);
            *(bvec8*)(dst + (size_t)p * 8) = pk.v;
        }
        return;
    }
    int t = (bid - 384) * 256 + tid;
    union { unsigned short us[8]; bvec8 v; } pk;
    if (t < 55296) {                        // apq (Wq scaled by tau*log2e)
        int u = t;
        int lane = u & 63;
        int t2 = u >> 6;
        int mf = t2 % 6, t3 = t2 / 6;
        int s = t3 % 18, g = t3 / 18;
        int kyx = s >> 1, icb = s & 1;
        int ky = kyx / 3, kx = kyx % 3;
        int m = mf * 16 + (lane & 15);
        int conv = m >> 5, cl = m & 31, co = g * 32 + cl;
        int ic0 = icb * 32 + (lane >> 4) * 8;
        const float* W = (conv == 0) ? Wq : (conv == 1 ? Wk : Wv);
        float scale = (conv == 0) ? tau[g] * 1.4426950408889634f : 1.f;
        #pragma unroll
        for (int j = 0; j < 8; ++j)
            pk.us[j] = f2bf(W[((co * 64 + ic0 + j) * 3 + ky) * 3 + kx] * scale);
        *(bvec8*)(apq + (size_t)u * 8) = pk.v;
    } else if (t < 59392) {                 // apx
        int u = t - 55296;
        int lane = u & 63;
        int t2 = u >> 6;
        int mf = t2 % 16, s = t2 / 16;
        int co = mf * 16 + (lane & 15);
        int k0 = s * 32 + (lane >> 4) * 8;
        #pragma unroll
        for (int j = 0; j < 8; ++j)
            pk.us[j] = f2bf(Wx[co * CIN + k0 + j]);
        *(bvec8*)(apx + (size_t)u * 8) = pk.v;
    } else if (t < 133120) {                // apg2
        int u = t - 59392;
        int lane = u & 63;
        int t2 = u >> 6;
        int mf = t2 % 8, t3 = t2 / 8;
        int s = t3 % 18, g = t3 / 18;
        int kyx = s >> 1, icb = s & 1;
        int ky = kyx / 3, kx = kyx % 3;
        int m = mf * 16 + (lane & 15);
        int gate = m >> 5, cl = m & 31, co = g * 32 + cl;
        int ic0 = icb * 32 + (lane >> 4) * 8;
        const float* W = (gate == 0) ? Wi2 : (gate == 1 ? Wf2 : (gate == 2 ? Wg2 : Wo2));
        #pragma unroll
        for (int j = 0; j < 8; ++j)
            pk.us[j] = f2bf(W[((co * 64 + ic0 + j) * 3 + ky) * 3 + kx]);
        *(bvec8*)(apg2 + (size_t)u * 8) = pk.v;
    } else if (t < 137216) {                // apg1
        int u = t - 133120;
        int lane = u & 63;
        int t2 = u >> 6;
        int mf = t2 % 8, g = t2 / 8;
        int m = mf * 16 + (lane & 15);
        int gate = m >> 5, cl = m & 31, co = g * 32 + cl;
        int k0 = (lane >> 4) * 8;
        const float* W = (gate == 0) ? Wi1 : (gate == 1 ? Wf1 : (gate == 2 ? Wg1 : Wo1));
        #pragma unroll
        for (int j = 0; j < 8; ++j)
            pk.us[j] = f2bf(W[co * 32 + k0 + j]);
        *(bvec8*)(apg1 + (size_t)u * 8) = pk.v;
    } else if (t < 145408) {                // zero vS tail (cols 1152..1183, all rows, all ng)
        int u = t - 137216;                  // 0..8191
        int ngb = u >> 7;                    // 0..63
        int rc = u & 127;
        int c = rc >> 2, cb = rc & 3;
        bvec8 z = {0, 0, 0, 0, 0, 0, 0, 0};
        *(bvec8*)(vS + (size_t)ngb * 37888 + (size_t)c * 1184 + 1152 + cb * 8) = z;
    }
}

// ---------------- kernel 1: xx = Wx·x as MFMA GEMM, interleaved bf16 out ----------------
__global__ __launch_bounds__(256) void k_xx_mfma(
        const unsigned short* __restrict__ xb, const unsigned short* __restrict__ apx,
        unsigned short* __restrict__ xxb) {
    int bid = blockIdx.x;
    int n = bid / 27, pc = bid % 27;
    int tid = threadIdx.x;
    int w = tid >> 6, lane = tid & 63;
    int ln = lane & 15, kgrp = lane >> 4;
    const bvec8* A = (const bvec8*)apx;
    bvec8 af[4][4];
    #pragma unroll
    for (int s = 0; s < 4; ++s)
        #pragma unroll
        for (int i = 0; i < 4; ++i)
            af[s][i] = A[(s * 16 + w * 4 + i) * 64 + lane];
    fvec4 acc[4][3];
    #pragma unroll
    for (int i = 0; i < 4; ++i)
        #pragma unroll
        for (int jn = 0; jn < 3; ++jn)
            acc[i][jn] = fvec4{0.f, 0.f, 0.f, 0.f};
    #pragma unroll
    for (int s = 0; s < 4; ++s) {
        #pragma unroll
        for (int jn = 0; jn < 3; ++jn) {
            int p = pc * 48 + jn * 16 + ln;
            bvec8 bfr = *(const bvec8*)(xb + ((size_t)(n * 16 + s * 4 + kgrp) * HW + p) * 8);
            #pragma unroll
            for (int i = 0; i < 4; ++i)
                acc[i][jn] = __builtin_amdgcn_mfma_f32_16x16x32_bf16(af[s][i], bfr, acc[i][jn], 0, 0, 0);
        }
    }
    #pragma unroll
    for (int i = 0; i < 4; ++i) {
        int co0 = (w * 4 + i) * 16 + kgrp * 4;
        int icb = co0 >> 3, sub = co0 & 7;
        #pragma unroll
        for (int jn = 0; jn < 3; ++jn) {
            int p = pc * 48 + jn * 16 + ln;
            union { unsigned short us[4]; unsigned long long u; } pk;
            #pragma unroll
            for (int r = 0; r < 4; ++r) pk.us[r] = f2bf(acc[i][jn][r]);
            *(unsigned long long*)(xxb + ((size_t)(n * 32 + icb) * HW + p) * 8 + sub) = pk.u;
        }
    }
}

// ---------------- kernel 2: MFMA grouped 3x3 conv -> qT, kT, vS (slot-permuted V) ----------------
__global__ __launch_bounds__(384) void k_qkv_mfma(
        const unsigned short* __restrict__ xxb, const unsigned short* __restrict__ h0b,
        const unsigned short* __restrict__ apq,
        unsigned short* __restrict__ qT, unsigned short* __restrict__ kT,
        unsigned short* __restrict__ vS) {
    int bid = blockIdx.x;
    int n = bid / 72, rem = bid % 72;
    int g = rem / 9, yt = rem % 9;
    __shared__ bvec8 sm[1824];
    int tid = threadIdx.x;
    for (int u = tid; u < 1824; u += 384) {
        int col = u % 38; int t2 = u / 38;
        int icb = t2 % 8; int rr = t2 / 8;
        int y = yt * 4 - 1 + rr, cx = col - 1;
        bvec8 val = {0, 0, 0, 0, 0, 0, 0, 0};
        if (y >= 0 && y < 36 && cx >= 0 && cx < 36) {
            const unsigned short* src = (icb < 4)
                ? (xxb + ((size_t)(n * 32 + g * 4 + icb) * HW) * 8)
                : (h0b + ((size_t)(n * 32 + g * 4 + icb - 4) * HW) * 8);
            val = *(const bvec8*)(src + (size_t)(y * 36 + cx) * 8);
        }
        int s = rr * 38 + col;
        sm[s * 8 + (icb ^ (s & 7))] = val;
    }
    __syncthreads();
    int lane = tid & 63, w = tid >> 6;
    int mg = w % 3, nh = w / 3;
    int kgrp = lane >> 4;
    int nf0 = nh * 4;
    int sb[5], pl[5];
    #pragma unroll
    for (int jn = 0; jn < 5; ++jn) {
        int p = (nf0 + jn) * 16 + (lane & 15);
        pl[jn] = p;
        sb[jn] = (p / 36) * 38 + (p % 36);
    }
    fvec4 acc[2][5];
    #pragma unroll
    for (int i = 0; i < 2; ++i)
        #pragma unroll
        for (int jn = 0; jn < 5; ++jn)
            acc[i][jn] = fvec4{0.f, 0.f, 0.f, 0.f};
    const bvec8* ap = (const bvec8*)apq + (size_t)g * 6912 + mg * 128 + lane;
    for (int s = 0; s < 18; ++s) {
        int kyx = s >> 1, icb = s & 1;
        int ky = kyx / 3, kx = kyx % 3;
        bvec8 a0 = ap[0], a1 = ap[64];
        ap += 384;
        int soff = ky * 38 + kx;
        int ib = icb * 4 + kgrp;
        #pragma unroll
        for (int jn = 0; jn < 5; ++jn) {
            int slot = sb[jn] + soff;
            bvec8 bfr = sm[slot * 8 + (ib ^ (slot & 7))];
            acc[0][jn] = __builtin_amdgcn_mfma_f32_16x16x32_bf16(a0, bfr, acc[0][jn], 0, 0, 0);
            acc[1][jn] = __builtin_amdgcn_mfma_f32_16x16x32_bf16(a1, bfr, acc[1][jn], 0, 0, 0);
        }
    }
    int ngb = n * 8 + g;
    unsigned short* qTg = qT + (size_t)ngb * 41472;
    unsigned short* kTg = kT + (size_t)ngb * 36992;
    unsigned short* vSg = vS + (size_t)ngb * 37888;
    #pragma unroll
    for (int i = 0; i < 2; ++i) {
        int mf = mg * 2 + i;
        int m0 = mf * 16 + kgrp * 4;
        int conv = m0 >> 5, c0 = m0 & 31;
        #pragma unroll
        for (int jn = 0; jn < 5; ++jn) {
            int gp = yt * 144 + pl[jn];
            int py = gp / 36, px = gp % 36;
            if (conv == 0) {
                union { unsigned short us[4]; unsigned long long u; } pk;
                #pragma unroll
                for (int r = 0; r < 4; ++r) pk.us[r] = f2bf(acc[i][jn][r]);
                *(unsigned long long*)(qTg + (size_t)gp * 32 + c0) = pk.u;
            } else if (py >= 1 && py <= 34 && px >= 1 && px <= 34) {
                int dpix = (py - 1) * 34 + (px - 1);
                if (conv == 1) {
                    union { unsigned short us[4]; unsigned long long u; } pk;
                    #pragma unroll
                    for (int r = 0; r < 4; ++r) pk.us[r] = f2bf(acc[i][jn][r]);
                    *(unsigned long long*)(kTg + (size_t)dpix * 32 + c0) = pk.u;
                } else {
                    int tt = dpix >> 5, kk = dpix & 31;
                    int slot = ((kk & 15) >> 2) * 8 + ((kk >> 4) << 2) + (kk & 3);
                    int idx = tt * 32 + slot;
                    #pragma unroll
                    for (int r = 0; r < 4; ++r)
                        vSg[(size_t)(c0 + r) * 1184 + idx] = f2bf(acc[i][jn][r]);
                }
            }
        }
    }
}

// ---------------- kernel 3: MFMA flash attention, depth-3 pipeline + XCD swizzle ----------------
#define ATTN_LOAD(ph, tt) \
    kb0##ph = *(const bvec8*)(kp + (tt) * 1024); \
    kb1##ph = *(const bvec8*)(kp + (tt) * 1024 + 512); \
    vb0##ph = *(const bvec8*)(vp + (tt) * 32); \
    vb1##ph = *(const bvec8*)(vp + (tt) * 32 + 18944);

#define ATTN_COMPUTE(ph) { \
    fvec4 s0 = __builtin_amdgcn_mfma_f32_16x16x32_bf16(kb0##ph, qf, zero, 0, 0, 0); \
    fvec4 s1 = __builtin_amdgcn_mfma_f32_16x16x32_bf16(kb1##ph, qf, zero, 0, 0, 0); \
    float p0 = exp2a(s0[0]), p1 = exp2a(s0[1]), p2 = exp2a(s0[2]), p3 = exp2a(s0[3]); \
    float p4 = exp2a(s1[0]), p5 = exp2a(s1[1]), p6 = exp2a(s1[2]), p7 = exp2a(s1[3]); \
    lp += ((p0 + p1) + (p2 + p3)) + ((p4 + p5) + (p6 + p7)); \
    union { unsigned int ui[4]; bvec8 v; } pB; \
    pB.ui[0] = cvtpk_bf16(p0, p1); \
    pB.ui[1] = cvtpk_bf16(p2, p3); \
    pB.ui[2] = cvtpk_bf16(p4, p5); \
    pB.ui[3] = cvtpk_bf16(p6, p7); \
    acc0 = __builtin_amdgcn_mfma_f32_16x16x32_bf16(vb0##ph, pB.v, acc0, 0, 0, 0); \
    acc1 = __builtin_amdgcn_mfma_f32_16x16x32_bf16(vb1##ph, pB.v, acc1, 0, 0, 0); }

__global__ __launch_bounds__(256) void k_attn_mfma(
        const unsigned short* __restrict__ qT, const unsigned short* __restrict__ kT,
        const unsigned short* __restrict__ vS, unsigned short* __restrict__ ab) {
    int bid = blockIdx.x;
    // XCD-aware bijective swizzle: all 21 blocks of one ng land on one XCD
    int r8 = bid & 7, q8 = bid >> 3;
    int bt = q8 % 21, ng = r8 + 8 * (q8 / 21);
    int tid = threadIdx.x;
    int w = tid >> 6, l = tid & 63;
    int qblk = bt * 4 + w;
    bool qvalid = qblk < 81;
    int qb = qvalid ? qblk : 80;
    int ln = l & 15, g = l >> 4;
    const unsigned short* qTg = qT + (size_t)ng * 41472;
    const unsigned short* kTg = kT + (size_t)ng * 36992;
    const unsigned short* vSg = vS + (size_t)ng * 37888;
    bvec8 qf = *(const bvec8*)(qTg + (size_t)(qb * 16 + ln) * 32 + g * 8);
    const unsigned short* kp = kTg + ln * 32 + g * 8;            // + t*1024 (+512 hi keys)
    const unsigned short* vp = vSg + (size_t)ln * 1184 + g * 8;  // + t*32 (+18944 ch 16..31)
    fvec4 acc0 = {0.f, 0.f, 0.f, 0.f}, acc1 = {0.f, 0.f, 0.f, 0.f};
    fvec4 zero = {0.f, 0.f, 0.f, 0.f};
    float lp = 0.f;
    bvec8 kb00, kb10, vb00, vb10;
    bvec8 kb01, kb11, vb01, vb11;
    bvec8 kb02, kb12, vb02, vb12;
    // tail fragments (keys 1152..1155; vS tail zero-filled by k_prep), loaded once
    bvec8 tk  = *(const bvec8*)(kTg + (size_t)min(1152 + ln, 1155) * 32 + g * 8);
    bvec8 tv0 = *(const bvec8*)(vp + 36 * 32);
    bvec8 tv1 = *(const bvec8*)(vp + 36 * 32 + 18944);
    ATTN_LOAD(0, 0)
    ATTN_LOAD(1, 1)
    ATTN_LOAD(2, 2)
    for (int tb = 0; tb < 33; tb += 3) {
        ATTN_COMPUTE(0) ATTN_LOAD(0, tb + 3)
        ATTN_COMPUTE(1) ATTN_LOAD(1, tb + 4)
        ATTN_COMPUTE(2) ATTN_LOAD(2, tb + 5)
    }
    ATTN_COMPUTE(0)
    ATTN_COMPUTE(1)
    ATTN_COMPUTE(2)
    {   // tail: keys 1152..1155 (lane's own A-dwords valid only for g==0)
        fvec4 s0 = __builtin_amdgcn_mfma_f32_16x16x32_bf16(tk, qf, zero, 0, 0, 0);
        float p0 = 0.f, p1 = 0.f, p2 = 0.f, p3 = 0.f;
        if (g == 0) {
            p0 = exp2a(s0[0]); p1 = exp2a(s0[1]);
            p2 = exp2a(s0[2]); p3 = exp2a(s0[3]);
        }
        lp += (p0 + p1) + (p2 + p3);
        union { unsigned int ui[4]; bvec8 v; } pB;
        pB.ui[0] = cvtpk_bf16(p0, p1);
        pB.ui[1] = cvtpk_bf16(p2, p3);
        pB.ui[2] = 0u;
        pB.ui[3] = 0u;
        acc0 = __builtin_amdgcn_mfma_f32_16x16x32_bf16(tv0, pB.v, acc0, 0, 0, 0);
        acc1 = __builtin_amdgcn_mfma_f32_16x16x32_bf16(tv1, pB.v, acc1, 0, 0, 0);
    }
    float lt = lp;
    lt += __shfl_xor(lt, 16, 64);
    lt += __shfl_xor(lt, 32, 64);
    float inv = 1.f / lt;
    if (qvalid) {
        int qpos = qblk * 16 + ln;
        unsigned short* ag = ab + (size_t)ng * 41472;
        int sub = (g & 1) * 4;
        union { unsigned short us[4]; unsigned long long u; } pk0, pk1;
        #pragma unroll
        for (int r = 0; r < 4; ++r) {
            pk0.us[r] = f2bf(acc0[r] * inv);
            pk1.us[r] = f2bf(acc1[r] * inv);
        }
        *(unsigned long long*)(ag + ((size_t)(g >> 1) * HW + qpos) * 8 + sub)       = pk0.u;
        *(unsigned long long*)(ag + ((size_t)(2 + (g >> 1)) * HW + qpos) * 8 + sub) = pk1.u;
    }
}

// ---------------- kernel 4: MFMA gates + LSTM combine ----------------
__global__ __launch_bounds__(256) void k_gates_mfma(
        const unsigned short* __restrict__ xxb, const unsigned short* __restrict__ h0b,
        const float* __restrict__ c0, const unsigned short* __restrict__ ab,
        const unsigned short* __restrict__ apg2, const unsigned short* __restrict__ apg1,
        const float* __restrict__ bi, const float* __restrict__ bf_,
        const float* __restrict__ bg, const float* __restrict__ bo,
        float* __restrict__ out) {
    int bid = blockIdx.x;
    int n = bid / 72, rem = bid % 72;
    int g = rem / 9, yt = rem % 9;
    __shared__ bvec8 smx[1824];
    __shared__ bvec8 sma[576];
    int tid = threadIdx.x;
    for (int u = tid; u < 1824; u += 256) {
        int col = u % 38; int t2 = u / 38;
        int icb = t2 % 8; int rr = t2 / 8;
        int y = yt * 4 - 1 + rr, cx = col - 1;
        bvec8 val = {0, 0, 0, 0, 0, 0, 0, 0};
        if (y >= 0 && y < 36 && cx >= 0 && cx < 36) {
            const unsigned short* src = (icb < 4)
                ? (xxb + ((size_t)(n * 32 + g * 4 + icb) * HW) * 8)
                : (h0b + ((size_t)(n * 32 + g * 4 + icb - 4) * HW) * 8);
            val = *(const bvec8*)(src + (size_t)(y * 36 + cx) * 8);
        }
        int s = rr * 38 + col;
        smx[s * 8 + (icb ^ (s & 7))] = val;
    }
    int ngb = n * 8 + g;
    for (int u = tid; u < 576; u += 256) {
        int p = u % 144, cb = u / 144;
        int gp = yt * 144 + p;
        bvec8 val = *(const bvec8*)(ab + ((size_t)(ngb * 4 + cb) * HW + gp) * 8);
        sma[p * 4 + (cb ^ (p & 3))] = val;
    }
    __syncthreads();
    int lane = tid & 63, w = tid >> 6;
    int b = w & 1, nh = w >> 1;
    int kgrp = lane >> 4, nf0 = nh * 4;
    int sb[5], pl[5];
    #pragma unroll
    for (int jn = 0; jn < 5; ++jn) {
        int p = (nf0 + jn) * 16 + (lane & 15);
        pl[jn] = p;
        sb[jn] = (p / 36) * 38 + (p % 36);
    }
    fvec4 acc[4][5];
    #pragma unroll
    for (int i = 0; i < 4; ++i)
        #pragma unroll
        for (int jn = 0; jn < 5; ++jn)
            acc[i][jn] = fvec4{0.f, 0.f, 0.f, 0.f};
    const bvec8* ap = (const bvec8*)apg2 + ((size_t)g * 144 + b) * 64 + lane;
    for (int s = 0; s < 18; ++s) {
        int kyx = s >> 1, icb = s & 1;
        int ky = kyx / 3, kx = kyx % 3;
        bvec8 a0 = ap[0], a1 = ap[128], a2 = ap[256], a3 = ap[384];
        ap += 512;
        int soff = ky * 38 + kx;
        int ib = icb * 4 + kgrp;
        #pragma unroll
        for (int jn = 0; jn < 5; ++jn) {
            int slot = sb[jn] + soff;
            bvec8 bfr = smx[slot * 8 + (ib ^ (slot & 7))];
            acc[0][jn] = __builtin_amdgcn_mfma_f32_16x16x32_bf16(a0, bfr, acc[0][jn], 0, 0, 0);
            acc[1][jn] = __builtin_amdgcn_mfma_f32_16x16x32_bf16(a1, bfr, acc[1][jn], 0, 0, 0);
            acc[2][jn] = __builtin_amdgcn_mfma_f32_16x16x32_bf16(a2, bfr, acc[2][jn], 0, 0, 0);
            acc[3][jn] = __builtin_amdgcn_mfma_f32_16x16x32_bf16(a3, bfr, acc[3][jn], 0, 0, 0);
        }
    }
    {
        const bvec8* ap1 = (const bvec8*)apg1 + ((size_t)g * 8 + b) * 64 + lane;
        bvec8 a0 = ap1[0], a1 = ap1[128], a2 = ap1[256], a3 = ap1[384];
        #pragma unroll
        for (int jn = 0; jn < 5; ++jn) {
            int p = pl[jn];
            bvec8 bfr = sma[p * 4 + (kgrp ^ (p & 3))];
            acc[0][jn] = __builtin_amdgcn_mfma_f32_16x16x32_bf16(a0, bfr, acc[0][jn], 0, 0, 0);
            acc[1][jn] = __builtin_amdgcn_mfma_f32_16x16x32_bf16(a1, bfr, acc[1][jn], 0, 0, 0);
            acc[2][jn] = __builtin_amdgcn_mfma_f32_16x16x32_bf16(a2, bfr, acc[2][jn], 0, 0, 0);
            acc[3][jn] = __builtin_amdgcn_mfma_f32_16x16x32_bf16(a3, bfr, acc[3][jn], 0, 0, 0);
        }
    }
    #pragma unroll
    for (int jn = 0; jn < 5; ++jn) {
        int gp = yt * 144 + pl[jn];
        #pragma unroll
        for (int r = 0; r < 4; ++r) {
            int cl = b * 16 + kgrp * 4 + r;
            int co = g * 32 + cl;
            float ip   = acc[0][jn][r] + bi[co];
            float fp   = acc[1][jn][r] + bf_[co];
            float gpre = acc[2][jn][r] + bg[co];
            float op   = acc[3][jn][r] + bo[co];
            float iv = sigmoidf_(ip), fv = sigmoidf_(fp);
            float gv = tanhf_(gpre), ov = sigmoidf_(op);
            float cv = fmaf(fv, c0[(size_t)(n * CC + co) * HW + gp], iv * gv);
            out[(size_t)(n * CC + co) * HW + gp] = ov * tanhf_(cv);
        }
    }
}

extern "C" void kernel_launch(void* const* d_in, const int* in_sizes, int n_in,
                              void* d_out, int out_size, void* d_ws, size_t ws_size,
                              hipStream_t stream) {
    const float* x   = (const float*)d_in[0];
    const float* h0  = (const float*)d_in[1];
    const float* c0  = (const float*)d_in[2];
    const float* Wx  = (const float*)d_in[3];
    const float* Wq  = (const float*)d_in[4];
    const float* Wk  = (const float*)d_in[5];
    const float* Wv  = (const float*)d_in[6];
    const float* Wi1 = (const float*)d_in[7];
    const float* Wi2 = (const float*)d_in[8];
    const float* bi  = (const float*)d_in[9];
    const float* Wf1 = (const float*)d_in[10];
    const float* Wf2 = (const float*)d_in[11];
    const float* bf  = (const float*)d_in[12];
    const float* Wg1 = (const float*)d_in[13];
    const float* Wg2 = (const float*)d_in[14];
    const float* bg  = (const float*)d_in[15];
    const float* Wo1 = (const float*)d_in[16];
    const float* Wo2 = (const float*)d_in[17];
    const float* bo  = (const float*)d_in[18];
    const float* tau = (const float*)d_in[19];

    unsigned short* ws  = (unsigned short*)d_ws;
    unsigned short* xb   = ws;                   // 1,327,104
    unsigned short* h0b  = xb   + 1327104;       // 2,654,208
    unsigned short* xxb  = h0b  + 2654208;       // 2,654,208
    unsigned short* ab   = xxb  + 2654208;       // 2,654,208
    unsigned short* qT   = ab   + 2654208;       // 2,654,208
    unsigned short* kT   = qT   + 2654208;       // 2,367,488
    unsigned short* vS   = kT   + 2367488;       // 2,424,832 (64 x 32 x 1184)
    unsigned short* apx  = vS   + 2424832;       // 32,768
    unsigned short* apq  = apx  + 32768;         // 442,368
    unsigned short* apg2 = apq  + 442368;        // 589,824
    unsigned short* apg1 = apg2 + 589824;        // 32,768
    float* out = (float*)d_out;

    hipLaunchKernelGGL(k_prep, dim3(952), dim3(256), 0, stream,
                       x, h0, Wx, Wq, Wk, Wv, tau,
                       Wi2, Wf2, Wg2, Wo2, Wi1, Wf1, Wg1, Wo1,
                       xb, h0b, apx, apq, apg2, apg1, vS);
    hipLaunchKernelGGL(k_xx_mfma,   dim3(216),  dim3(256), 0, stream, xb, apx, xxb);
    hipLaunchKernelGGL(k_qkv_mfma,  dim3(576),  dim3(384), 0, stream, xxb, h0b, apq, qT, kT, vS);
    hipLaunchKernelGGL(k_attn_mfma, dim3(1344), dim3(256), 0, stream, qT, kT, vS, ab);
    hipLaunchKernelGGL(k_gates_mfma,dim3(576),  dim3(256), 0, stream, xxb, h0b, c0, ab,
                       apg2, apg1, bi, bf, bg, bo, out);
}

// Round 13
// 127.449 us; speedup vs baseline: 1.0576x; 1.0286x over previous
//
#include <hip/hip_runtime.h>
#include <math.h>

#define NN  8
#define CIN 128
#define HW  1296
#define CC  256
#define DDS 1156

typedef __attribute__((ext_vector_type(8))) short bvec8;
typedef __attribute__((ext_vector_type(4))) float fvec4;

__device__ __forceinline__ float sigmoidf_(float x) {
    return 1.f / (1.f + __expf(-x));
}
__device__ __forceinline__ float tanhf_(float x) {
    float xa = fminf(fmaxf(x, -15.f), 15.f);
    float e = __expf(2.f * xa);
    return (e - 1.f) / (e + 1.f);
}
__device__ __forceinline__ unsigned short f2bf(float f) {
    unsigned int u = __float_as_uint(f);
    u = (u + 0x7FFFu + ((u >> 16) & 1u)) >> 16;
    return (unsigned short)u;
}
__device__ __forceinline__ unsigned int cvtpk_bf16(float a, float b) {
    unsigned int r;
    asm("v_cvt_pk_bf16_f32 %0, %1, %2" : "=v"(r) : "v"(a), "v"(b));
    return r;   // lo16 = bf16(a), hi16 = bf16(b), RTNE
}
__device__ __forceinline__ float exp2a(float x) {   // 2^x, single v_exp_f32
    float r;
    asm("v_exp_f32 %0, %1" : "=v"(r) : "v"(x));
    return r;
}

// ---------------- kernel 0: prep ----------------
// blocks 0..383: LDS-transpose x/h0 -> interleaved bf16
// blocks 384..951: pack weights + ZERO vS tail tile (slots for keys 1152..1183)
__global__ __launch_bounds__(256) void k_prep(
        const float* __restrict__ x, const float* __restrict__ h0,
        const float* __restrict__ Wx,
        const float* __restrict__ Wq, const float* __restrict__ Wk,
        const float* __restrict__ Wv, const float* __restrict__ tau,
        const float* __restrict__ Wi2, const float* __restrict__ Wf2,
        const float* __restrict__ Wg2, const float* __restrict__ Wo2,
        const float* __restrict__ Wi1, const float* __restrict__ Wf1,
        const float* __restrict__ Wg1, const float* __restrict__ Wo1,
        unsigned short* __restrict__ xb, unsigned short* __restrict__ h0b,
        unsigned short* __restrict__ apx, unsigned short* __restrict__ apq,
        unsigned short* __restrict__ apg2, unsigned short* __restrict__ apg1,
        unsigned short* __restrict__ vS) {
    __shared__ float tr[10400];          // 8 ch x stride 1300 (bank-clean)
    int bid = blockIdx.x;
    int tid = threadIdx.x;
    if (bid < 384) {
        int n = bid / 48, cb = bid % 48;
        const float* src = (cb < 16) ? x  + (size_t)(n * CIN + cb * 8) * HW
                                     : h0 + (size_t)(n * CC + (cb - 16) * 8) * HW;
        unsigned short* dst = (cb < 16) ? xb  + ((size_t)(n * 16 + cb) * HW) * 8
                                        : h0b + ((size_t)(n * 32 + (cb - 16)) * HW) * 8;
        #pragma unroll
        for (int c = 0; c < 8; ++c)
            for (int p4 = tid; p4 < 324; p4 += 256) {
                float4 v = ((const float4*)(src + (size_t)c * HW))[p4];
                *(float4*)&tr[c * 1300 + p4 * 4] = v;
            }
        __syncthreads();
        for (int p = tid; p < 1296; p += 256) {
            union { unsigned short us[8]; bvec8 v; } pk;
            #pragma unroll
            for (int c = 0; c < 8; ++c) pk.us[c] = f2bf(tr[c * 1300 + p]);
            *(bvec8*)(dst + (size_t)p * 8) = pk.v;
        }
        return;
    }
    int t = (bid - 384) * 256 + tid;
    union { unsigned short us[8]; bvec8 v; } pk;
    if (t < 55296) {                        // apq (Wq scaled by tau*log2e)
        int u = t;
        int lane = u & 63;
        int t2 = u >> 6;
        int mf = t2 % 6, t3 = t2 / 6;
        int s = t3 % 18, g = t3 / 18;
        int kyx = s >> 1, icb = s & 1;
        int ky = kyx / 3, kx = kyx % 3;
        int m = mf * 16 + (lane & 15);
        int conv = m >> 5, cl = m & 31, co = g * 32 + cl;
        int ic0 = icb * 32 + (lane >> 4) * 8;
        const float* W = (conv == 0) ? Wq : (conv == 1 ? Wk : Wv);
        float scale = (conv == 0) ? tau[g] * 1.4426950408889634f : 1.f;
        #pragma unroll
        for (int j = 0; j < 8; ++j)
            pk.us[j] = f2bf(W[((co * 64 + ic0 + j) * 3 + ky) * 3 + kx] * scale);
        *(bvec8*)(apq + (size_t)u * 8) = pk.v;
    } else if (t < 59392) {                 // apx
        int u = t - 55296;
        int lane = u & 63;
        int t2 = u >> 6;
        int mf = t2 % 16, s = t2 / 16;
        int co = mf * 16 + (lane & 15);
        int k0 = s * 32 + (lane >> 4) * 8;
        #pragma unroll
        for (int j = 0; j < 8; ++j)
            pk.us[j] = f2bf(Wx[co * CIN + k0 + j]);
        *(bvec8*)(apx + (size_t)u * 8) = pk.v;
    } else if (t < 133120) {                // apg2
        int u = t - 59392;
        int lane = u & 63;
        int t2 = u >> 6;
        int mf = t2 % 8, t3 = t2 / 8;
        int s = t3 % 18, g = t3 / 18;
        int kyx = s >> 1, icb = s & 1;
        int ky = kyx / 3, kx = kyx % 3;
        int m = mf * 16 + (lane & 15);
        int gate = m >> 5, cl = m & 31, co = g * 32 + cl;
        int ic0 = icb * 32 + (lane >> 4) * 8;
        const float* W = (gate == 0) ? Wi2 : (gate == 1 ? Wf2 : (gate == 2 ? Wg2 : Wo2));
        #pragma unroll
        for (int j = 0; j < 8; ++j)
            pk.us[j] = f2bf(W[((co * 64 + ic0 + j) * 3 + ky) * 3 + kx]);
        *(bvec8*)(apg2 + (size_t)u * 8) = pk.v;
    } else if (t < 137216) {                // apg1
        int u = t - 133120;
        int lane = u & 63;
        int t2 = u >> 6;
        int mf = t2 % 8, g = t2 / 8;
        int m = mf * 16 + (lane & 15);
        int gate = m >> 5, cl = m & 31, co = g * 32 + cl;
        int k0 = (lane >> 4) * 8;
        const float* W = (gate == 0) ? Wi1 : (gate == 1 ? Wf1 : (gate == 2 ? Wg1 : Wo1));
        #pragma unroll
        for (int j = 0; j < 8; ++j)
            pk.us[j] = f2bf(W[co * 32 + k0 + j]);
        *(bvec8*)(apg1 + (size_t)u * 8) = pk.v;
    } else if (t < 145408) {                // zero vS tail (cols 1152..1183, all rows, all ng)
        int u = t - 137216;                  // 0..8191
        int ngb = u >> 7;                    // 0..63
        int rc = u & 127;
        int c = rc >> 2, cb = rc & 3;
        bvec8 z = {0, 0, 0, 0, 0, 0, 0, 0};
        *(bvec8*)(vS + (size_t)ngb * 37888 + (size_t)c * 1184 + 1152 + cb * 8) = z;
    }
}

// ---------------- kernel 1: xx = Wx·x as MFMA GEMM, interleaved bf16 out ----------------
__global__ __launch_bounds__(256) void k_xx_mfma(
        const unsigned short* __restrict__ xb, const unsigned short* __restrict__ apx,
        unsigned short* __restrict__ xxb) {
    int bid = blockIdx.x;
    int n = bid / 27, pc = bid % 27;
    int tid = threadIdx.x;
    int w = tid >> 6, lane = tid & 63;
    int ln = lane & 15, kgrp = lane >> 4;
    const bvec8* A = (const bvec8*)apx;
    bvec8 af[4][4];
    #pragma unroll
    for (int s = 0; s < 4; ++s)
        #pragma unroll
        for (int i = 0; i < 4; ++i)
            af[s][i] = A[(s * 16 + w * 4 + i) * 64 + lane];
    fvec4 acc[4][3];
    #pragma unroll
    for (int i = 0; i < 4; ++i)
        #pragma unroll
        for (int jn = 0; jn < 3; ++jn)
            acc[i][jn] = fvec4{0.f, 0.f, 0.f, 0.f};
    #pragma unroll
    for (int s = 0; s < 4; ++s) {
        #pragma unroll
        for (int jn = 0; jn < 3; ++jn) {
            int p = pc * 48 + jn * 16 + ln;
            bvec8 bfr = *(const bvec8*)(xb + ((size_t)(n * 16 + s * 4 + kgrp) * HW + p) * 8);
            #pragma unroll
            for (int i = 0; i < 4; ++i)
                acc[i][jn] = __builtin_amdgcn_mfma_f32_16x16x32_bf16(af[s][i], bfr, acc[i][jn], 0, 0, 0);
        }
    }
    #pragma unroll
    for (int i = 0; i < 4; ++i) {
        int co0 = (w * 4 + i) * 16 + kgrp * 4;
        int icb = co0 >> 3, sub = co0 & 7;
        #pragma unroll
        for (int jn = 0; jn < 3; ++jn) {
            int p = pc * 48 + jn * 16 + ln;
            union { unsigned short us[4]; unsigned long long u; } pk;
            #pragma unroll
            for (int r = 0; r < 4; ++r) pk.us[r] = f2bf(acc[i][jn][r]);
            *(unsigned long long*)(xxb + ((size_t)(n * 32 + icb) * HW + p) * 8 + sub) = pk.u;
        }
    }
}

// ---------------- kernel 2: MFMA grouped 3x3 conv -> qT, kT, vS (slot-permuted V) ----------------
__global__ __launch_bounds__(384) void k_qkv_mfma(
        const unsigned short* __restrict__ xxb, const unsigned short* __restrict__ h0b,
        const unsigned short* __restrict__ apq,
        unsigned short* __restrict__ qT, unsigned short* __restrict__ kT,
        unsigned short* __restrict__ vS) {
    int bid = blockIdx.x;
    int n = bid / 72, rem = bid % 72;
    int g = rem / 9, yt = rem % 9;
    __shared__ bvec8 sm[1824];
    int tid = threadIdx.x;
    for (int u = tid; u < 1824; u += 384) {
        int col = u % 38; int t2 = u / 38;
        int icb = t2 % 8; int rr = t2 / 8;
        int y = yt * 4 - 1 + rr, cx = col - 1;
        bvec8 val = {0, 0, 0, 0, 0, 0, 0, 0};
        if (y >= 0 && y < 36 && cx >= 0 && cx < 36) {
            const unsigned short* src = (icb < 4)
                ? (xxb + ((size_t)(n * 32 + g * 4 + icb) * HW) * 8)
                : (h0b + ((size_t)(n * 32 + g * 4 + icb - 4) * HW) * 8);
            val = *(const bvec8*)(src + (size_t)(y * 36 + cx) * 8);
        }
        int s = rr * 38 + col;
        sm[s * 8 + (icb ^ (s & 7))] = val;
    }
    __syncthreads();
    int lane = tid & 63, w = tid >> 6;
    int mg = w % 3, nh = w / 3;
    int kgrp = lane >> 4;
    int nf0 = nh * 4;
    int sb[5], pl[5];
    #pragma unroll
    for (int jn = 0; jn < 5; ++jn) {
        int p = (nf0 + jn) * 16 + (lane & 15);
        pl[jn] = p;
        sb[jn] = (p / 36) * 38 + (p % 36);
    }
    fvec4 acc[2][5];
    #pragma unroll
    for (int i = 0; i < 2; ++i)
        #pragma unroll
        for (int jn = 0; jn < 5; ++jn)
            acc[i][jn] = fvec4{0.f, 0.f, 0.f, 0.f};
    const bvec8* ap = (const bvec8*)apq + (size_t)g * 6912 + mg * 128 + lane;
    for (int s = 0; s < 18; ++s) {
        int kyx = s >> 1, icb = s & 1;
        int ky = kyx / 3, kx = kyx % 3;
        bvec8 a0 = ap[0], a1 = ap[64];
        ap += 384;
        int soff = ky * 38 + kx;
        int ib = icb * 4 + kgrp;
        #pragma unroll
        for (int jn = 0; jn < 5; ++jn) {
            int slot = sb[jn] + soff;
            bvec8 bfr = sm[slot * 8 + (ib ^ (slot & 7))];
            acc[0][jn] = __builtin_amdgcn_mfma_f32_16x16x32_bf16(a0, bfr, acc[0][jn], 0, 0, 0);
            acc[1][jn] = __builtin_amdgcn_mfma_f32_16x16x32_bf16(a1, bfr, acc[1][jn], 0, 0, 0);
        }
    }
    int ngb = n * 8 + g;
    unsigned short* qTg = qT + (size_t)ngb * 41472;
    unsigned short* kTg = kT + (size_t)ngb * 36992;
    unsigned short* vSg = vS + (size_t)ngb * 37888;
    #pragma unroll
    for (int i = 0; i < 2; ++i) {
        int mf = mg * 2 + i;
        int m0 = mf * 16 + kgrp * 4;
        int conv = m0 >> 5, c0 = m0 & 31;
        #pragma unroll
        for (int jn = 0; jn < 5; ++jn) {
            int gp = yt * 144 + pl[jn];
            int py = gp / 36, px = gp % 36;
            if (conv == 0) {
                union { unsigned short us[4]; unsigned long long u; } pk;
                #pragma unroll
                for (int r = 0; r < 4; ++r) pk.us[r] = f2bf(acc[i][jn][r]);
                *(unsigned long long*)(qTg + (size_t)gp * 32 + c0) = pk.u;
            } else if (py >= 1 && py <= 34 && px >= 1 && px <= 34) {
                int dpix = (py - 1) * 34 + (px - 1);
                if (conv == 1) {
                    union { unsigned short us[4]; unsigned long long u; } pk;
                    #pragma unroll
                    for (int r = 0; r < 4; ++r) pk.us[r] = f2bf(acc[i][jn][r]);
                    *(unsigned long long*)(kTg + (size_t)dpix * 32 + c0) = pk.u;
                } else {
                    int tt = dpix >> 5, kk = dpix & 31;
                    int slot = ((kk & 15) >> 2) * 8 + ((kk >> 4) << 2) + (kk & 3);
                    int idx = tt * 32 + slot;
                    #pragma unroll
                    for (int r = 0; r < 4; ++r)
                        vSg[(size_t)(c0 + r) * 1184 + idx] = f2bf(acc[i][jn][r]);
                }
            }
        }
    }
}

// ---------------- kernel 3: MFMA flash attention, depth-3 pipeline + XCD swizzle ----------------
// 1-wave blocks (occupancy experiment); wave-level code verbatim from the verified R11 kernel.
#define ATTN_LOAD(ph, tt) \
    kb0##ph = *(const bvec8*)(kp + (tt) * 1024); \
    kb1##ph = *(const bvec8*)(kp + (tt) * 1024 + 512); \
    vb0##ph = *(const bvec8*)(vp + (tt) * 32); \
    vb1##ph = *(const bvec8*)(vp + (tt) * 32 + 18944);

#define ATTN_COMPUTE(ph) { \
    fvec4 s0 = __builtin_amdgcn_mfma_f32_16x16x32_bf16(kb0##ph, qf, zero, 0, 0, 0); \
    fvec4 s1 = __builtin_amdgcn_mfma_f32_16x16x32_bf16(kb1##ph, qf, zero, 0, 0, 0); \
    float p0 = exp2a(s0[0]), p1 = exp2a(s0[1]), p2 = exp2a(s0[2]), p3 = exp2a(s0[3]); \
    float p4 = exp2a(s1[0]), p5 = exp2a(s1[1]), p6 = exp2a(s1[2]), p7 = exp2a(s1[3]); \
    lp += ((p0 + p1) + (p2 + p3)) + ((p4 + p5) + (p6 + p7)); \
    union { unsigned int ui[4]; bvec8 v; } pB; \
    pB.ui[0] = cvtpk_bf16(p0, p1); \
    pB.ui[1] = cvtpk_bf16(p2, p3); \
    pB.ui[2] = cvtpk_bf16(p4, p5); \
    pB.ui[3] = cvtpk_bf16(p6, p7); \
    acc0 = __builtin_amdgcn_mfma_f32_16x16x32_bf16(vb0##ph, pB.v, acc0, 0, 0, 0); \
    acc1 = __builtin_amdgcn_mfma_f32_16x16x32_bf16(vb1##ph, pB.v, acc1, 0, 0, 0); }

__global__ __launch_bounds__(64) void k_attn_mfma(
        const unsigned short* __restrict__ qT, const unsigned short* __restrict__ kT,
        const unsigned short* __restrict__ vS, unsigned short* __restrict__ ab) {
    int bid = blockIdx.x;
    // grid 5184 = 8 x 648 (648 = 81 x 8): all 81 q-blocks of one ng on one XCD
    int r8 = bid & 7, q8 = bid >> 3;
    int qblk = q8 % 81, ng = r8 + 8 * (q8 / 81);
    int tid = threadIdx.x;
    int l = tid & 63;
    bool qvalid = qblk < 81;    // always true (kept for structural identity)
    int qb = qvalid ? qblk : 80;
    int ln = l & 15, g = l >> 4;
    const unsigned short* qTg = qT + (size_t)ng * 41472;
    const unsigned short* kTg = kT + (size_t)ng * 36992;
    const unsigned short* vSg = vS + (size_t)ng * 37888;
    bvec8 qf = *(const bvec8*)(qTg + (size_t)(qb * 16 + ln) * 32 + g * 8);
    const unsigned short* kp = kTg + ln * 32 + g * 8;            // + t*1024 (+512 hi keys)
    const unsigned short* vp = vSg + (size_t)ln * 1184 + g * 8;  // + t*32 (+18944 ch 16..31)
    fvec4 acc0 = {0.f, 0.f, 0.f, 0.f}, acc1 = {0.f, 0.f, 0.f, 0.f};
    fvec4 zero = {0.f, 0.f, 0.f, 0.f};
    float lp = 0.f;
    bvec8 kb00, kb10, vb00, vb10;
    bvec8 kb01, kb11, vb01, vb11;
    bvec8 kb02, kb12, vb02, vb12;
    // tail fragments (keys 1152..1155; vS tail zero-filled by k_prep), loaded once
    bvec8 tk  = *(const bvec8*)(kTg + (size_t)min(1152 + ln, 1155) * 32 + g * 8);
    bvec8 tv0 = *(const bvec8*)(vp + 36 * 32);
    bvec8 tv1 = *(const bvec8*)(vp + 36 * 32 + 18944);
    ATTN_LOAD(0, 0)
    ATTN_LOAD(1, 1)
    ATTN_LOAD(2, 2)
    for (int tb = 0; tb < 33; tb += 3) {
        ATTN_COMPUTE(0) ATTN_LOAD(0, tb + 3)
        ATTN_COMPUTE(1) ATTN_LOAD(1, tb + 4)
        ATTN_COMPUTE(2) ATTN_LOAD(2, tb + 5)
    }
    ATTN_COMPUTE(0)
    ATTN_COMPUTE(1)
    ATTN_COMPUTE(2)
    {   // tail: keys 1152..1155 (lane's own A-dwords valid only for g==0)
        fvec4 s0 = __builtin_amdgcn_mfma_f32_16x16x32_bf16(tk, qf, zero, 0, 0, 0);
        float p0 = 0.f, p1 = 0.f, p2 = 0.f, p3 = 0.f;
        if (g == 0) {
            p0 = exp2a(s0[0]); p1 = exp2a(s0[1]);
            p2 = exp2a(s0[2]); p3 = exp2a(s0[3]);
        }
        lp += (p0 + p1) + (p2 + p3);
        union { unsigned int ui[4]; bvec8 v; } pB;
        pB.ui[0] = cvtpk_bf16(p0, p1);
        pB.ui[1] = cvtpk_bf16(p2, p3);
        pB.ui[2] = 0u;
        pB.ui[3] = 0u;
        acc0 = __builtin_amdgcn_mfma_f32_16x16x32_bf16(tv0, pB.v, acc0, 0, 0, 0);
        acc1 = __builtin_amdgcn_mfma_f32_16x16x32_bf16(tv1, pB.v, acc1, 0, 0, 0);
    }
    float lt = lp;
    lt += __shfl_xor(lt, 16, 64);
    lt += __shfl_xor(lt, 32, 64);
    float inv = 1.f / lt;
    if (qvalid) {
        int qpos = qblk * 16 + ln;
        unsigned short* ag = ab + (size_t)ng * 41472;
        int sub = (g & 1) * 4;
        union { unsigned short us[4]; unsigned long long u; } pk0, pk1;
        #pragma unroll
        for (int r = 0; r < 4; ++r) {
            pk0.us[r] = f2bf(acc0[r] * inv);
            pk1.us[r] = f2bf(acc1[r] * inv);
        }
        *(unsigned long long*)(ag + ((size_t)(g >> 1) * HW + qpos) * 8 + sub)       = pk0.u;
        *(unsigned long long*)(ag + ((size_t)(2 + (g >> 1)) * HW + qpos) * 8 + sub) = pk1.u;
    }
}

// ---------------- kernel 4: MFMA gates + LSTM combine ----------------
__global__ __launch_bounds__(256) void k_gates_mfma(
        const unsigned short* __restrict__ xxb, const unsigned short* __restrict__ h0b,
        const float* __restrict__ c0, const unsigned short* __restrict__ ab,
        const unsigned short* __restrict__ apg2, const unsigned short* __restrict__ apg1,
        const float* __restrict__ bi, const float* __restrict__ bf_,
        const float* __restrict__ bg, const float* __restrict__ bo,
        float* __restrict__ out) {
    int bid = blockIdx.x;
    int n = bid / 72, rem = bid % 72;
    int g = rem / 9, yt = rem % 9;
    __shared__ bvec8 smx[1824];
    __shared__ bvec8 sma[576];
    int tid = threadIdx.x;
    for (int u = tid; u < 1824; u += 256) {
        int col = u % 38; int t2 = u / 38;
        int icb = t2 % 8; int rr = t2 / 8;
        int y = yt * 4 - 1 + rr, cx = col - 1;
        bvec8 val = {0, 0, 0, 0, 0, 0, 0, 0};
        if (y >= 0 && y < 36 && cx >= 0 && cx < 36) {
            const unsigned short* src = (icb < 4)
                ? (xxb + ((size_t)(n * 32 + g * 4 + icb) * HW) * 8)
                : (h0b + ((size_t)(n * 32 + g * 4 + icb - 4) * HW) * 8);
            val = *(const bvec8*)(src + (size_t)(y * 36 + cx) * 8);
        }
        int s = rr * 38 + col;
        smx[s * 8 + (icb ^ (s & 7))] = val;
    }
    int ngb = n * 8 + g;
    for (int u = tid; u < 576; u += 256) {
        int p = u % 144, cb = u / 144;
        int gp = yt * 144 + p;
        bvec8 val = *(const bvec8*)(ab + ((size_t)(ngb * 4 + cb) * HW + gp) * 8);
        sma[p * 4 + (cb ^ (p & 3))] = val;
    }
    __syncthreads();
    int lane = tid & 63, w = tid >> 6;
    int b = w & 1, nh = w >> 1;
    int kgrp = lane >> 4, nf0 = nh * 4;
    int sb[5], pl[5];
    #pragma unroll
    for (int jn = 0; jn < 5; ++jn) {
        int p = (nf0 + jn) * 16 + (lane & 15);
        pl[jn] = p;
        sb[jn] = (p / 36) * 38 + (p % 36);
    }
    fvec4 acc[4][5];
    #pragma unroll
    for (int i = 0; i < 4; ++i)
        #pragma unroll
        for (int jn = 0; jn < 5; ++jn)
            acc[i][jn] = fvec4{0.f, 0.f, 0.f, 0.f};
    const bvec8* ap = (const bvec8*)apg2 + ((size_t)g * 144 + b) * 64 + lane;
    for (int s = 0; s < 18; ++s) {
        int kyx = s >> 1, icb = s & 1;
        int ky = kyx / 3, kx = kyx % 3;
        bvec8 a0 = ap[0], a1 = ap[128], a2 = ap[256], a3 = ap[384];
        ap += 512;
        int soff = ky * 38 + kx;
        int ib = icb * 4 + kgrp;
        #pragma unroll
        for (int jn = 0; jn < 5; ++jn) {
            int slot = sb[jn] + soff;
            bvec8 bfr = smx[slot * 8 + (ib ^ (slot & 7))];
            acc[0][jn] = __builtin_amdgcn_mfma_f32_16x16x32_bf16(a0, bfr, acc[0][jn], 0, 0, 0);
            acc[1][jn] = __builtin_amdgcn_mfma_f32_16x16x32_bf16(a1, bfr, acc[1][jn], 0, 0, 0);
            acc[2][jn] = __builtin_amdgcn_mfma_f32_16x16x32_bf16(a2, bfr, acc[2][jn], 0, 0, 0);
            acc[3][jn] = __builtin_amdgcn_mfma_f32_16x16x32_bf16(a3, bfr, acc[3][jn], 0, 0, 0);
        }
    }
    {
        const bvec8* ap1 = (const bvec8*)apg1 + ((size_t)g * 8 + b) * 64 + lane;
        bvec8 a0 = ap1[0], a1 = ap1[128], a2 = ap1[256], a3 = ap1[384];
        #pragma unroll
        for (int jn = 0; jn < 5; ++jn) {
            int p = pl[jn];
            bvec8 bfr = sma[p * 4 + (kgrp ^ (p & 3))];
            acc[0][jn] = __builtin_amdgcn_mfma_f32_16x16x32_bf16(a0, bfr, acc[0][jn], 0, 0, 0);
            acc[1][jn] = __builtin_amdgcn_mfma_f32_16x16x32_bf16(a1, bfr, acc[1][jn], 0, 0, 0);
            acc[2][jn] = __builtin_amdgcn_mfma_f32_16x16x32_bf16(a2, bfr, acc[2][jn], 0, 0, 0);
            acc[3][jn] = __builtin_amdgcn_mfma_f32_16x16x32_bf16(a3, bfr, acc[3][jn], 0, 0, 0);
        }
    }
    #pragma unroll
    for (int jn = 0; jn < 5; ++jn) {
        int gp = yt * 144 + pl[jn];
        #pragma unroll
        for (int r = 0; r < 4; ++r) {
            int cl = b * 16 + kgrp * 4 + r;
            int co = g * 32 + cl;
            float ip   = acc[0][jn][r] + bi[co];
            float fp   = acc[1][jn][r] + bf_[co];
            float gpre = acc[2][jn][r] + bg[co];
            float op   = acc[3][jn][r] + bo[co];
            float iv = sigmoidf_(ip), fv = sigmoidf_(fp);
            float gv = tanhf_(gpre), ov = sigmoidf_(op);
            float cv = fmaf(fv, c0[(size_t)(n * CC + co) * HW + gp], iv * gv);
            out[(size_t)(n * CC + co) * HW + gp] = ov * tanhf_(cv);
        }
    }
}

extern "C" void kernel_launch(void* const* d_in, const int* in_sizes, int n_in,
                              void* d_out, int out_size, void* d_ws, size_t ws_size,
                              hipStream_t stream) {
    const float* x   = (const float*)d_in[0];
    const float* h0  = (const float*)d_in[1];
    const float* c0  = (const float*)d_in[2];
    const float* Wx  = (const float*)d_in[3];
    const float* Wq  = (const float*)d_in[4];
    const float* Wk  = (const float*)d_in[5];
    const float* Wv  = (const float*)d_in[6];
    const float* Wi1 = (const float*)d_in[7];
    const float* Wi2 = (const float*)d_in[8];
    const float* bi  = (const float*)d_in[9];
    const float* Wf1 = (const float*)d_in[10];
    const float* Wf2 = (const float*)d_in[11];
    const float* bf  = (const float*)d_in[12];
    const float* Wg1 = (const float*)d_in[13];
    const float* Wg2 = (const float*)d_in[14];
    const float* bg  = (const float*)d_in[15];
    const float* Wo1 = (const float*)d_in[16];
    const float* Wo2 = (const float*)d_in[17];
    const float* bo  = (const float*)d_in[18];
    const float* tau = (const float*)d_in[19];

    unsigned short* ws  = (unsigned short*)d_ws;
    unsigned short* xb   = ws;                   // 1,327,104
    unsigned short* h0b  = xb   + 1327104;       // 2,654,208
    unsigned short* xxb  = h0b  + 2654208;       // 2,654,208
    unsigned short* ab   = xxb  + 2654208;       // 2,654,208
    unsigned short* qT   = ab   + 2654208;       // 2,654,208
    unsigned short* kT   = qT   + 2654208;       // 2,367,488
    unsigned short* vS   = kT   + 2367488;       // 2,424,832 (64 x 32 x 1184)
    unsigned short* apx  = vS   + 2424832;       // 32,768
    unsigned short* apq  = apx  + 32768;         // 442,368
    unsigned short* apg2 = apq  + 442368;        // 589,824
    unsigned short* apg1 = apg2 + 589824;        // 32,768
    float* out = (float*)d_out;

    hipLaunchKernelGGL(k_prep, dim3(952), dim3(256), 0, stream,
                       x, h0, Wx, Wq, Wk, Wv, tau,
                       Wi2, Wf2, Wg2, Wo2, Wi1, Wf1, Wg1, Wo1,
                       xb, h0b, apx, apq, apg2, apg1, vS);
    hipLaunchKernelGGL(k_xx_mfma,   dim3(216),  dim3(256), 0, stream, xb, apx, xxb);
    hipLaunchKernelGGL(k_qkv_mfma,  dim3(576),  dim3(384), 0, stream, xxb, h0b, apq, qT, kT, vS);
    hipLaunchKernelGGL(k_attn_mfma, dim3(5184), dim3(64),  0, stream, qT, kT, vS, ab);
    hipLaunchKernelGGL(k_gates_mfma,dim3(576),  dim3(256), 0, stream, xxb, h0b, c0, ab,
                       apg2, apg1, bi, bf, bg, bo, out);
}